// Round 1
// baseline (1508.038 us; speedup 1.0000x reference)
//
#include <hip/hip_runtime.h>
#include <math.h>

// ---------------------------------------------------------------------------
// Nystromformer layer, round 1: all-fp32 correctness-first implementation.
// b=4, n=8192, DIM=512, HEADS=2, DH=64, M=256 landmarks (chunks of 32).
// Rem = n % M == 0 -> no padding path; out[:, -n:] is identity.
// out = x + ( concat_h[ softmax(q k_l^T) @ (pinv(a2) @ (softmax(q_l k^T) @ v))
//                       + depthwise_conv33(v) ] ) @ w_out + b_out
// ---------------------------------------------------------------------------

#define BB 4
#define HH 2
#define NSEQ 8192
#define DMODEL 512
#define DH 64
#define MLAND 256
#define LCH 32
#define W3 384
#define INNER 128
#define KER 33
#define BH (BB*HH)

// ---------------------------------------------------------------------------
// K1: fused LayerNorm + QKV GEMM (32 rows/block). q scaled by DH^-0.5.
// q/k/v written in head layout [b][h][n][d].
// ---------------------------------------------------------------------------
__global__ __launch_bounds__(256) void ln_qkv_kernel(
    const float* __restrict__ x, const float* __restrict__ gamma,
    const float* __restrict__ beta, const float* __restrict__ wqkv,
    float* __restrict__ q, float* __restrict__ k, float* __restrict__ v)
{
    __shared__ float xn[32][513];   // +1 pad: (r*513+k)%32 spreads banks
    __shared__ float gs[512];
    __shared__ float bs[512];
    const int t = threadIdx.x;
    const int row0 = blockIdx.x * 32;

    for (int i = t; i < 512; i += 256) { gs[i] = gamma[i]; bs[i] = beta[i]; }
    __syncthreads();

    const int wave = t >> 6;
    const int lane = t & 63;
    #pragma unroll 1
    for (int i = 0; i < 8; ++i) {
        const int r = wave * 8 + i;
        const float* xr = x + (size_t)(row0 + r) * DMODEL + lane * 8;
        const float4 a = *(const float4*)(xr);
        const float4 b = *(const float4*)(xr + 4);
        float s  = a.x + a.y + a.z + a.w + b.x + b.y + b.z + b.w;
        float ss = a.x*a.x + a.y*a.y + a.z*a.z + a.w*a.w
                 + b.x*b.x + b.y*b.y + b.z*b.z + b.w*b.w;
        #pragma unroll
        for (int o = 32; o > 0; o >>= 1) {
            s  += __shfl_xor(s, o, 64);
            ss += __shfl_xor(ss, o, 64);
        }
        const float mu = s * (1.0f/512.0f);
        const float var = ss * (1.0f/512.0f) - mu*mu;
        const float rstd = rsqrtf(var + 1e-5f);
        const int c = lane * 8;
        xn[r][c+0] = (a.x - mu) * rstd * gs[c+0] + bs[c+0];
        xn[r][c+1] = (a.y - mu) * rstd * gs[c+1] + bs[c+1];
        xn[r][c+2] = (a.z - mu) * rstd * gs[c+2] + bs[c+2];
        xn[r][c+3] = (a.w - mu) * rstd * gs[c+3] + bs[c+3];
        xn[r][c+4] = (b.x - mu) * rstd * gs[c+4] + bs[c+4];
        xn[r][c+5] = (b.y - mu) * rstd * gs[c+5] + bs[c+5];
        xn[r][c+6] = (b.z - mu) * rstd * gs[c+6] + bs[c+6];
        xn[r][c+7] = (b.w - mu) * rstd * gs[c+7] + bs[c+7];
    }
    __syncthreads();

    const int c0 = (t & 63) * 6;        // 64 groups * 6 = 384 cols
    const int r0 = (t >> 6) * 8;        // 4 groups * 8 = 32 rows
    float acc[8][6];
    #pragma unroll
    for (int i = 0; i < 8; ++i)
        #pragma unroll
        for (int j = 0; j < 6; ++j) acc[i][j] = 0.0f;

    #pragma unroll 4
    for (int kk = 0; kk < 512; ++kk) {
        const float* wrow = wqkv + (size_t)kk * W3 + c0;
        const float w0 = wrow[0], w1 = wrow[1], w2 = wrow[2];
        const float w3 = wrow[3], w4 = wrow[4], w5 = wrow[5];
        #pragma unroll
        for (int i = 0; i < 8; ++i) {
            const float xv = xn[r0+i][kk];
            acc[i][0] = fmaf(xv, w0, acc[i][0]);
            acc[i][1] = fmaf(xv, w1, acc[i][1]);
            acc[i][2] = fmaf(xv, w2, acc[i][2]);
            acc[i][3] = fmaf(xv, w3, acc[i][3]);
            acc[i][4] = fmaf(xv, w4, acc[i][4]);
            acc[i][5] = fmaf(xv, w5, acc[i][5]);
        }
    }

    #pragma unroll
    for (int i = 0; i < 8; ++i) {
        const int grow = row0 + r0 + i;
        const int b = grow >> 13;             // / NSEQ
        const int n = grow & (NSEQ - 1);
        #pragma unroll
        for (int j = 0; j < 6; ++j) {
            const int c = c0 + j;
            const float val = acc[i][j];
            if (c < INNER) {
                const int h = c >> 6, d = c & 63;
                q[(((size_t)b*HH + h)*NSEQ + n)*DH + d] = val * 0.125f;
            } else if (c < 2*INNER) {
                const int cc = c - INNER;
                const int h = cc >> 6, d = cc & 63;
                k[(((size_t)b*HH + h)*NSEQ + n)*DH + d] = val;
            } else {
                const int cc = c - 2*INNER;
                const int h = cc >> 6, d = cc & 63;
                v[(((size_t)b*HH + h)*NSEQ + n)*DH + d] = val;
            }
        }
    }
}

// ---------------------------------------------------------------------------
// K2: landmark means over chunks of 32 rows. block = 4 landmarks x 64 d.
// ---------------------------------------------------------------------------
__global__ __launch_bounds__(256) void landmark_kernel(
    const float* __restrict__ q, const float* __restrict__ k,
    float* __restrict__ ql, float* __restrict__ kl)
{
    const int t = threadIdx.x;
    const int g = blockIdx.x * 4 + (t >> 6);      // landmark id in [0, BH*M)
    const int d = t & 63;
    const int bh = g >> 8;
    const int m  = g & 255;
    const float* qb = q + ((size_t)bh * NSEQ + (size_t)m * LCH) * DH + d;
    const float* kb = k + ((size_t)bh * NSEQ + (size_t)m * LCH) * DH + d;
    float sq = 0.0f, sk = 0.0f;
    #pragma unroll
    for (int i = 0; i < LCH; ++i) { sq += qb[i*DH]; sk += kb[i*DH]; }
    ql[((size_t)bh * MLAND + m) * DH + d] = sq * (1.0f/LCH);
    kl[((size_t)bh * MLAND + m) * DH + d] = sk * (1.0f/LCH);
}

// ---------------------------------------------------------------------------
// K3: a2 = softmax(q_l @ k_l^T). One block per (bh, row i); thread j = col.
// ---------------------------------------------------------------------------
__global__ __launch_bounds__(256) void sim2_kernel(
    const float* __restrict__ ql, const float* __restrict__ kl,
    float* __restrict__ a2)
{
    const int bh = blockIdx.x >> 8;
    const int i  = blockIdx.x & 255;
    const int j  = threadIdx.x;
    __shared__ float qrow[64];
    __shared__ float red[8];
    if (j < 64) qrow[j] = ql[((size_t)bh*MLAND + i)*DH + j];
    __syncthreads();
    const float4* k4 = (const float4*)(kl + ((size_t)bh*MLAND + j)*DH);
    float s = 0.0f;
    #pragma unroll
    for (int u = 0; u < 16; ++u) {
        const float4 kv = k4[u];
        s = fmaf(qrow[u*4+0], kv.x, s);
        s = fmaf(qrow[u*4+1], kv.y, s);
        s = fmaf(qrow[u*4+2], kv.z, s);
        s = fmaf(qrow[u*4+3], kv.w, s);
    }
    float m = s;
    #pragma unroll
    for (int o = 32; o > 0; o >>= 1) m = fmaxf(m, __shfl_xor(m, o, 64));
    if ((j & 63) == 0) red[j >> 6] = m;
    __syncthreads();
    m = fmaxf(fmaxf(red[0], red[1]), fmaxf(red[2], red[3]));
    const float e = __expf(s - m);
    float l = e;
    #pragma unroll
    for (int o = 32; o > 0; o >>= 1) l += __shfl_xor(l, o, 64);
    if ((j & 63) == 0) red[4 + (j >> 6)] = l;
    __syncthreads();
    l = red[4] + red[5] + red[6] + red[7];
    a2[((size_t)bh*MLAND + i)*MLAND + j] = e / l;
}

// ---------------------------------------------------------------------------
// K4: pinv init. Global max of row-abs-sums and col-abs-sums (over ALL bh,
// matching jnp.max without axis), then z0 = a2^T / (mr*mc).
// ---------------------------------------------------------------------------
__global__ void initmax_kernel(unsigned int* mx) {
    if (threadIdx.x < 2) mx[threadIdx.x] = 0u;
}

__global__ __launch_bounds__(256) void pinv_sums_kernel(
    const float* __restrict__ a2, unsigned int* __restrict__ mx)
{
    const int bh = blockIdx.x;
    const int t = threadIdx.x;
    const float* A = a2 + (size_t)bh * MLAND * MLAND;
    float rs = 0.0f, cs = 0.0f;
    const float4* row4 = (const float4*)(A + (size_t)t * MLAND);
    #pragma unroll 8
    for (int u = 0; u < 64; ++u) {
        const float4 val = row4[u];
        rs += fabsf(val.x) + fabsf(val.y) + fabsf(val.z) + fabsf(val.w);
    }
    #pragma unroll 8
    for (int i = 0; i < MLAND; ++i) cs += fabsf(A[(size_t)i*MLAND + t]);
    __shared__ float red[8];
    float mrs = rs, mcs = cs;
    #pragma unroll
    for (int o = 32; o > 0; o >>= 1) {
        mrs = fmaxf(mrs, __shfl_xor(mrs, o, 64));
        mcs = fmaxf(mcs, __shfl_xor(mcs, o, 64));
    }
    if ((t & 63) == 0) { red[t>>6] = mrs; red[4+(t>>6)] = mcs; }
    __syncthreads();
    if (t == 0) {
        const float a = fmaxf(fmaxf(red[0],red[1]), fmaxf(red[2],red[3]));
        const float b = fmaxf(fmaxf(red[4],red[5]), fmaxf(red[6],red[7]));
        atomicMax(&mx[0], __float_as_uint(a));
        atomicMax(&mx[1], __float_as_uint(b));
    }
}

__global__ __launch_bounds__(256) void z0_kernel(
    const float* __restrict__ a2, const unsigned int* __restrict__ mx,
    float* __restrict__ z)
{
    const float scale = 1.0f / (__uint_as_float(mx[0]) * __uint_as_float(mx[1]));
    const size_t idx = (size_t)blockIdx.x * 256 + threadIdx.x;
    const size_t bh = idx >> 16;
    const size_t i = (idx >> 8) & 255;
    const size_t j = idx & 255;
    z[idx] = a2[(bh << 16) | (j << 8) | i] * scale;
}

// ---------------------------------------------------------------------------
// K5: batched (8x) 256x256 @ 256xNC:  C = c1*A + c2*(A@B).
// Newton stages: XZ=A@B; T1=7XZ-XZ@XZ; T2=15XZ-XZ@T1; Z'=3.25Z-0.25Z@T2.
// Tile 32x64, 2x4 per thread.
// ---------------------------------------------------------------------------
__global__ __launch_bounds__(256) void mm256_kernel(
    float* __restrict__ C, const float* __restrict__ A,
    const float* __restrict__ Bm, float c1, float c2, int NC)
{
    __shared__ float As[32][65];
    __shared__ float Bs[64][68];
    const int bh = blockIdx.z;
    const int row0 = blockIdx.y * 32;
    const int col0 = blockIdx.x * 64;
    const float* Ab = A + (size_t)bh * MLAND * MLAND;
    const float* Bb = Bm + (size_t)bh * MLAND * NC;
    const int t = threadIdx.x;
    const int tc = (t & 15) * 4;
    const int tr = (t >> 4) * 2;
    float acc[2][4] = {{0,0,0,0},{0,0,0,0}};
    for (int k0 = 0; k0 < 256; k0 += 64) {
        #pragma unroll
        for (int u = 0; u < 2; ++u) {
            const int idx = t + u*256;
            const int r = idx >> 4, c4 = (idx & 15) * 4;
            const float4 val = *(const float4*)(Ab + (size_t)(row0 + r) * MLAND + k0 + c4);
            As[r][c4+0] = val.x; As[r][c4+1] = val.y;
            As[r][c4+2] = val.z; As[r][c4+3] = val.w;
        }
        #pragma unroll
        for (int u = 0; u < 4; ++u) {
            const int idx = t + u*256;
            const int r = idx >> 4, c4 = (idx & 15) * 4;
            *(float4*)&Bs[r][c4] = *(const float4*)(Bb + (size_t)(k0 + r) * NC + col0 + c4);
        }
        __syncthreads();
        #pragma unroll 8
        for (int kk = 0; kk < 64; ++kk) {
            const float a0 = As[tr][kk];
            const float a1 = As[tr+1][kk];
            const float4 b4 = *(const float4*)&Bs[kk][tc];
            acc[0][0] = fmaf(a0, b4.x, acc[0][0]);
            acc[0][1] = fmaf(a0, b4.y, acc[0][1]);
            acc[0][2] = fmaf(a0, b4.z, acc[0][2]);
            acc[0][3] = fmaf(a0, b4.w, acc[0][3]);
            acc[1][0] = fmaf(a1, b4.x, acc[1][0]);
            acc[1][1] = fmaf(a1, b4.y, acc[1][1]);
            acc[1][2] = fmaf(a1, b4.z, acc[1][2]);
            acc[1][3] = fmaf(a1, b4.w, acc[1][3]);
        }
        __syncthreads();
    }
    #pragma unroll
    for (int i = 0; i < 2; ++i) {
        const int r = row0 + tr + i;
        #pragma unroll
        for (int j = 0; j < 4; ++j) {
            const int c = col0 + tc + j;
            float val = c2 * acc[i][j];
            if (c1 != 0.0f) val = fmaf(c1, Ab[(size_t)r * MLAND + c], val);
            C[((size_t)bh * MLAND + r) * NC + c] = val;
        }
    }
}

// ---------------------------------------------------------------------------
// K6: flash-style a3v partials. Block = (bh, 256-col chunk); thread = q_l row.
// q row in registers; k/v 64-row subchunks in LDS (broadcast reads).
// Online softmax in batches of 16 columns.
// ---------------------------------------------------------------------------
__global__ __launch_bounds__(256, 1) void sim3_kernel(
    const float* __restrict__ ql, const float* __restrict__ kg,
    const float* __restrict__ vg, float* __restrict__ po,
    float* __restrict__ pm, float* __restrict__ pl)
{
    __shared__ float ks[64][68];
    __shared__ float vs[64][68];
    const int ch = blockIdx.x;
    const int bh = blockIdx.y;
    const int t = threadIdx.x;
    float4 q4[16];
    {
        const float* qr = ql + ((size_t)bh * MLAND + t) * DH;
        #pragma unroll
        for (int u = 0; u < 16; ++u) q4[u] = *(const float4*)(qr + u*4);
    }
    float4 o4[16];
    #pragma unroll
    for (int u = 0; u < 16; ++u) o4[u] = make_float4(0.f,0.f,0.f,0.f);
    float m = -1e30f, l = 0.0f;

    #pragma unroll 1
    for (int sc = 0; sc < 4; ++sc) {
        const int j0 = ch * 256 + sc * 64;
        #pragma unroll
        for (int u = 0; u < 4; ++u) {
            const int idx = t + u*256;
            const int r = idx >> 4, c4 = (idx & 15) * 4;
            *(float4*)&ks[r][c4] = *(const float4*)(kg + ((size_t)bh*NSEQ + j0 + r)*DH + c4);
            *(float4*)&vs[r][c4] = *(const float4*)(vg + ((size_t)bh*NSEQ + j0 + r)*DH + c4);
        }
        __syncthreads();
        #pragma unroll 1
        for (int b16 = 0; b16 < 4; ++b16) {
            float s[16];
            #pragma unroll
            for (int c = 0; c < 16; ++c) {
                const int cc = b16*16 + c;
                float a = 0.0f;
                #pragma unroll
                for (int u = 0; u < 16; ++u) {
                    const float4 kv = *(const float4*)&ks[cc][u*4];
                    a = fmaf(q4[u].x, kv.x, a);
                    a = fmaf(q4[u].y, kv.y, a);
                    a = fmaf(q4[u].z, kv.z, a);
                    a = fmaf(q4[u].w, kv.w, a);
                }
                s[c] = a;
            }
            float bm = s[0];
            #pragma unroll
            for (int c = 1; c < 16; ++c) bm = fmaxf(bm, s[c]);
            const float mn = fmaxf(m, bm);
            const float scale = __expf(m - mn);
            l *= scale;
            #pragma unroll
            for (int u = 0; u < 16; ++u) {
                o4[u].x *= scale; o4[u].y *= scale;
                o4[u].z *= scale; o4[u].w *= scale;
            }
            #pragma unroll
            for (int c = 0; c < 16; ++c) {
                const int cc = b16*16 + c;
                const float p = __expf(s[c] - mn);
                l += p;
                #pragma unroll
                for (int u = 0; u < 16; ++u) {
                    const float4 vv = *(const float4*)&vs[cc][u*4];
                    o4[u].x = fmaf(p, vv.x, o4[u].x);
                    o4[u].y = fmaf(p, vv.y, o4[u].y);
                    o4[u].z = fmaf(p, vv.z, o4[u].z);
                    o4[u].w = fmaf(p, vv.w, o4[u].w);
                }
            }
            m = mn;
        }
        __syncthreads();
    }
    float* od = po + (((size_t)bh*32 + ch) * MLAND + t) * DH;
    #pragma unroll
    for (int u = 0; u < 16; ++u) *(float4*)(od + u*4) = o4[u];
    pm[((size_t)bh*32 + ch) * MLAND + t] = m;
    pl[((size_t)bh*32 + ch) * MLAND + t] = l;
}

// K7: merge 32 chunk partials -> a3v = softmax(q_l k^T) @ v
__global__ __launch_bounds__(256) void sim3red_kernel(
    const float* __restrict__ po, const float* __restrict__ pm,
    const float* __restrict__ pl, float* __restrict__ a3v)
{
    const int g = blockIdx.x * 4 + (threadIdx.x >> 6);
    const int d = threadIdx.x & 63;
    const int bh = g >> 8;
    const int r = g & 255;
    float M = -1e30f;
    #pragma unroll
    for (int c = 0; c < 32; ++c)
        M = fmaxf(M, pm[((size_t)bh*32 + c)*MLAND + r]);
    float L = 0.0f, o = 0.0f;
    #pragma unroll 1
    for (int c = 0; c < 32; ++c) {
        const float w = __expf(pm[((size_t)bh*32 + c)*MLAND + r] - M);
        L = fmaf(pl[((size_t)bh*32 + c)*MLAND + r], w, L);
        o = fmaf(po[(((size_t)bh*32 + c)*MLAND + r)*DH + d], w, o);
    }
    a3v[((size_t)bh*MLAND + r)*DH + d] = o / L;
}

// ---------------------------------------------------------------------------
// K8: per-row sim1 softmax @ W + depthwise conv residual -> inner[b][n][128].
// Block = (64-row tile, bh); 4 rows processed simultaneously.
// ---------------------------------------------------------------------------
__global__ __launch_bounds__(256, 1) void final1_kernel(
    const float* __restrict__ q, const float* __restrict__ vg,
    const float* __restrict__ kl, const float* __restrict__ Wm,
    const float* __restrict__ wres, float* __restrict__ inner)
{
    __shared__ float kls[256][65];
    __shared__ float Ws[256][65];
    __shared__ float qs[4][64];
    __shared__ float ps[4][256];
    __shared__ float opart[4][4][64];
    __shared__ float red[4][8];
    __shared__ float Ls[4];
    __shared__ float wr[KER];
    const int bh = blockIdx.y;
    const int h = bh & 1;
    const int b = bh >> 1;
    const int t = threadIdx.x;
    #pragma unroll 4
    for (int u = 0; u < 64; ++u) {
        const int idx = t + u*256;
        const int rr = idx >> 6, dd = idx & 63;
        kls[rr][dd] = kl[(size_t)bh*MLAND*DH + idx];
        Ws[rr][dd]  = Wm[(size_t)bh*MLAND*DH + idx];
    }
    if (t < KER) wr[t] = wres[h*KER + t];
    __syncthreads();

    #pragma unroll 1
    for (int rg = 0; rg < 16; ++rg) {
        const int n0 = blockIdx.x * 64 + rg * 4;
        qs[t>>6][t&63] = q[((size_t)bh*NSEQ + n0 + (t>>6))*DH + (t&63)];
        __syncthreads();
        float s0=0.f, s1=0.f, s2=0.f, s3=0.f;
        #pragma unroll 8
        for (int d = 0; d < 64; ++d) {
            const float kv = kls[t][d];
            s0 = fmaf(qs[0][d], kv, s0);
            s1 = fmaf(qs[1][d], kv, s1);
            s2 = fmaf(qs[2][d], kv, s2);
            s3 = fmaf(qs[3][d], kv, s3);
        }
        float m0=s0, m1=s1, m2=s2, m3=s3;
        #pragma unroll
        for (int o = 32; o > 0; o >>= 1) {
            m0 = fmaxf(m0, __shfl_xor(m0,o,64));
            m1 = fmaxf(m1, __shfl_xor(m1,o,64));
            m2 = fmaxf(m2, __shfl_xor(m2,o,64));
            m3 = fmaxf(m3, __shfl_xor(m3,o,64));
        }
        if ((t & 63) == 0) {
            red[0][t>>6]=m0; red[1][t>>6]=m1; red[2][t>>6]=m2; red[3][t>>6]=m3;
        }
        __syncthreads();
        m0 = fmaxf(fmaxf(red[0][0],red[0][1]), fmaxf(red[0][2],red[0][3]));
        m1 = fmaxf(fmaxf(red[1][0],red[1][1]), fmaxf(red[1][2],red[1][3]));
        m2 = fmaxf(fmaxf(red[2][0],red[2][1]), fmaxf(red[2][2],red[2][3]));
        m3 = fmaxf(fmaxf(red[3][0],red[3][1]), fmaxf(red[3][2],red[3][3]));
        const float p0 = __expf(s0 - m0);
        const float p1 = __expf(s1 - m1);
        const float p2 = __expf(s2 - m2);
        const float p3 = __expf(s3 - m3);
        ps[0][t]=p0; ps[1][t]=p1; ps[2][t]=p2; ps[3][t]=p3;
        float l0=p0, l1=p1, l2=p2, l3=p3;
        #pragma unroll
        for (int o = 32; o > 0; o >>= 1) {
            l0 += __shfl_xor(l0,o,64);
            l1 += __shfl_xor(l1,o,64);
            l2 += __shfl_xor(l2,o,64);
            l3 += __shfl_xor(l3,o,64);
        }
        if ((t & 63) == 0) {
            red[0][4+(t>>6)]=l0; red[1][4+(t>>6)]=l1;
            red[2][4+(t>>6)]=l2; red[3][4+(t>>6)]=l3;
        }
        __syncthreads();
        if (t == 0) {
            Ls[0] = red[0][4]+red[0][5]+red[0][6]+red[0][7];
            Ls[1] = red[1][4]+red[1][5]+red[1][6]+red[1][7];
            Ls[2] = red[2][4]+red[2][5]+red[2][6]+red[2][7];
            Ls[3] = red[3][4]+red[3][5]+red[3][6]+red[3][7];
        }
        __syncthreads();
        const int d = t & 63;
        const int jg = t >> 6;
        float o0=0.f, o1=0.f, o2=0.f, o3=0.f;
        #pragma unroll 8
        for (int jj = 0; jj < 64; ++jj) {
            const int j = jg*64 + jj;
            const float wv = Ws[j][d];
            o0 = fmaf(ps[0][j], wv, o0);
            o1 = fmaf(ps[1][j], wv, o1);
            o2 = fmaf(ps[2][j], wv, o2);
            o3 = fmaf(ps[3][j], wv, o3);
        }
        opart[jg][0][d]=o0; opart[jg][1][d]=o1; opart[jg][2][d]=o2; opart[jg][3][d]=o3;
        __syncthreads();
        {
            const int rr = t >> 6;
            const int n = n0 + rr;
            float o = (opart[0][rr][d] + opart[1][rr][d]
                     + opart[2][rr][d] + opart[3][rr][d]) / Ls[rr];
            float rconv = 0.0f;
            #pragma unroll 1
            for (int tt = 0; tt < KER; ++tt) {
                const int nn = n - 16 + tt;
                if (nn >= 0 && nn < NSEQ)
                    rconv = fmaf(vg[((size_t)bh*NSEQ + nn)*DH + d], wr[tt], rconv);
            }
            inner[((size_t)b*NSEQ + n)*INNER + h*DH + d] = o + rconv;
        }
        __syncthreads();
    }
}

// K9: out = inner @ w_out + b_out + x. Tile 32x512, 8x8 per thread.
__global__ __launch_bounds__(256) void final2_kernel(
    const float* __restrict__ inner, const float* __restrict__ wout,
    const float* __restrict__ bout, const float* __restrict__ x,
    float* __restrict__ out)
{
    __shared__ float is[32][129];
    const int t = threadIdx.x;
    const size_t row0 = (size_t)blockIdx.x * 32;
    #pragma unroll
    for (int u = 0; u < 4; ++u) {
        const int idx = t + u*256;
        const int r = idx >> 5, c4 = (idx & 31) * 4;
        const float4 val = *(const float4*)(inner + (row0 + r)*INNER + c4);
        is[r][c4+0]=val.x; is[r][c4+1]=val.y; is[r][c4+2]=val.z; is[r][c4+3]=val.w;
    }
    __syncthreads();
    const int c0 = (t & 63) * 8;
    const int r0 = (t >> 6) * 8;
    float acc[8][8];
    #pragma unroll
    for (int i = 0; i < 8; ++i)
        #pragma unroll
        for (int j = 0; j < 8; ++j) acc[i][j] = 0.0f;
    #pragma unroll 2
    for (int kk = 0; kk < 128; ++kk) {
        const float4 w0 = *(const float4*)(wout + (size_t)kk*DMODEL + c0);
        const float4 w1 = *(const float4*)(wout + (size_t)kk*DMODEL + c0 + 4);
        #pragma unroll
        for (int i = 0; i < 8; ++i) {
            const float xv = is[r0+i][kk];
            acc[i][0] = fmaf(xv, w0.x, acc[i][0]);
            acc[i][1] = fmaf(xv, w0.y, acc[i][1]);
            acc[i][2] = fmaf(xv, w0.z, acc[i][2]);
            acc[i][3] = fmaf(xv, w0.w, acc[i][3]);
            acc[i][4] = fmaf(xv, w1.x, acc[i][4]);
            acc[i][5] = fmaf(xv, w1.y, acc[i][5]);
            acc[i][6] = fmaf(xv, w1.z, acc[i][6]);
            acc[i][7] = fmaf(xv, w1.w, acc[i][7]);
        }
    }
    const float4 b0 = *(const float4*)(bout + c0);
    const float4 b1 = *(const float4*)(bout + c0 + 4);
    #pragma unroll
    for (int i = 0; i < 8; ++i) {
        const size_t row = row0 + r0 + i;
        const float4 x0 = *(const float4*)(x + row*DMODEL + c0);
        const float4 x1 = *(const float4*)(x + row*DMODEL + c0 + 4);
        float4 o0, o1;
        o0.x = acc[i][0] + b0.x + x0.x;
        o0.y = acc[i][1] + b0.y + x0.y;
        o0.z = acc[i][2] + b0.z + x0.z;
        o0.w = acc[i][3] + b0.w + x0.w;
        o1.x = acc[i][4] + b1.x + x1.x;
        o1.y = acc[i][5] + b1.y + x1.y;
        o1.z = acc[i][6] + b1.z + x1.z;
        o1.w = acc[i][7] + b1.w + x1.w;
        *(float4*)(out + row*DMODEL + c0) = o0;
        *(float4*)(out + row*DMODEL + c0 + 4) = o1;
    }
}

// ---------------------------------------------------------------------------
extern "C" void kernel_launch(void* const* d_in, const int* in_sizes, int n_in,
                              void* d_out, int out_size, void* d_ws, size_t ws_size,
                              hipStream_t stream)
{
    const float* x     = (const float*)d_in[0];
    const float* gamma = (const float*)d_in[1];
    const float* beta  = (const float*)d_in[2];
    const float* wqkv  = (const float*)d_in[3];
    const float* wout  = (const float*)d_in[4];
    const float* bout  = (const float*)d_in[5];
    const float* wres  = (const float*)d_in[6];
    float* out = (float*)d_out;

    float* ws = (float*)d_ws;
    const size_t QS = (size_t)BH * NSEQ * DH;       // 4194304
    const size_t LS = (size_t)BH * MLAND * DH;      // 131072
    const size_t MS = (size_t)BH * MLAND * MLAND;   // 524288
    float* q    = ws;
    float* kbuf = q + QS;
    float* vbuf = kbuf + QS;
    float* ql   = vbuf + QS;
    float* klm  = ql + LS;
    float* a2   = klm + LS;
    float* zA   = a2 + MS;
    float* zB   = zA + MS;
    float* xz   = zB + MS;
    float* t1   = xz + MS;
    float* t2   = t1 + MS;
    float* a3v  = t2 + MS;
    float* Wm   = a3v + LS;
    float* po   = Wm + LS;                          // 4194304 floats
    float* pm   = po + QS;
    float* pl   = pm + (size_t)BH * 32 * MLAND;
    unsigned int* mx = (unsigned int*)(pl + (size_t)BH * 32 * MLAND);
    float* inner = po;   // alias: po dead after sim3red, inner born in final1

    ln_qkv_kernel<<<(BB*NSEQ)/32, 256, 0, stream>>>(x, gamma, beta, wqkv, q, kbuf, vbuf);
    landmark_kernel<<<(BH*MLAND)/4, 256, 0, stream>>>(q, kbuf, ql, klm);
    sim2_kernel<<<BH*MLAND, 256, 0, stream>>>(ql, klm, a2);

    // a3v (independent of pinv)
    sim3_kernel<<<dim3(32, BH), 256, 0, stream>>>(ql, kbuf, vbuf, po, pm, pl);
    sim3red_kernel<<<(BH*MLAND)/4, 256, 0, stream>>>(po, pm, pl, a3v);

    // pinv of a2 (6 Newton iterations, fp32)
    initmax_kernel<<<1, 64, 0, stream>>>(mx);
    pinv_sums_kernel<<<BH, 256, 0, stream>>>(a2, mx);
    z0_kernel<<<(unsigned)(MS/256), 256, 0, stream>>>(a2, mx, zA);
    float* za = zA;
    float* zb = zB;
    for (int it = 0; it < 6; ++it) {
        mm256_kernel<<<dim3(4,8,BH), 256, 0, stream>>>(xz, a2, za, 0.0f, 1.0f, 256);
        mm256_kernel<<<dim3(4,8,BH), 256, 0, stream>>>(t1, xz, xz, 7.0f, -1.0f, 256);
        mm256_kernel<<<dim3(4,8,BH), 256, 0, stream>>>(t2, xz, t1, 15.0f, -1.0f, 256);
        mm256_kernel<<<dim3(4,8,BH), 256, 0, stream>>>(zb, za, t2, 3.25f, -0.25f, 256);
        float* tmp = za; za = zb; zb = tmp;
    }
    // W = a2_inv @ a3v
    mm256_kernel<<<dim3(1,8,BH), 256, 0, stream>>>(Wm, za, a3v, 0.0f, 1.0f, 64);

    final1_kernel<<<dim3(NSEQ/64, BH), 256, 0, stream>>>(q, vbuf, klm, Wm, wres, inner);
    final2_kernel<<<(BB*NSEQ)/32, 256, 0, stream>>>(inner, wout, bout, x, out);
}

// Round 2
// 1128.773 us; speedup vs baseline: 1.3360x; 1.3360x over previous
//
#include <hip/hip_runtime.h>
#include <math.h>

// ---------------------------------------------------------------------------
// Nystromformer layer, round 2: final1 -> bf16 MFMA flash attention (KV=256),
// conv split into separate += kernel. Everything else unchanged from round 1.
// ---------------------------------------------------------------------------

#define BB 4
#define HH 2
#define NSEQ 8192
#define DMODEL 512
#define DH 64
#define MLAND 256
#define LCH 32
#define W3 384
#define INNER 128
#define KER 33
#define BH (BB*HH)

typedef __attribute__((ext_vector_type(8))) short short8v;
typedef __attribute__((ext_vector_type(4))) short short4v;
typedef __attribute__((ext_vector_type(4))) float f32x4;

__device__ __forceinline__ short f2bf(float f) {
    unsigned u = __float_as_uint(f);
    u = (u + 0x7FFFu + ((u >> 16) & 1u)) >> 16;
    return (short)u;
}

// ---------------------------------------------------------------------------
// K1: fused LayerNorm + QKV GEMM (32 rows/block). q scaled by DH^-0.5.
// ---------------------------------------------------------------------------
__global__ __launch_bounds__(256) void ln_qkv_kernel(
    const float* __restrict__ x, const float* __restrict__ gamma,
    const float* __restrict__ beta, const float* __restrict__ wqkv,
    float* __restrict__ q, float* __restrict__ k, float* __restrict__ v)
{
    __shared__ float xn[32][513];
    __shared__ float gs[512];
    __shared__ float bs[512];
    const int t = threadIdx.x;
    const int row0 = blockIdx.x * 32;

    for (int i = t; i < 512; i += 256) { gs[i] = gamma[i]; bs[i] = beta[i]; }
    __syncthreads();

    const int wave = t >> 6;
    const int lane = t & 63;
    #pragma unroll 1
    for (int i = 0; i < 8; ++i) {
        const int r = wave * 8 + i;
        const float* xr = x + (size_t)(row0 + r) * DMODEL + lane * 8;
        const float4 a = *(const float4*)(xr);
        const float4 b = *(const float4*)(xr + 4);
        float s  = a.x + a.y + a.z + a.w + b.x + b.y + b.z + b.w;
        float ss = a.x*a.x + a.y*a.y + a.z*a.z + a.w*a.w
                 + b.x*b.x + b.y*b.y + b.z*b.z + b.w*b.w;
        #pragma unroll
        for (int o = 32; o > 0; o >>= 1) {
            s  += __shfl_xor(s, o, 64);
            ss += __shfl_xor(ss, o, 64);
        }
        const float mu = s * (1.0f/512.0f);
        const float var = ss * (1.0f/512.0f) - mu*mu;
        const float rstd = rsqrtf(var + 1e-5f);
        const int c = lane * 8;
        xn[r][c+0] = (a.x - mu) * rstd * gs[c+0] + bs[c+0];
        xn[r][c+1] = (a.y - mu) * rstd * gs[c+1] + bs[c+1];
        xn[r][c+2] = (a.z - mu) * rstd * gs[c+2] + bs[c+2];
        xn[r][c+3] = (a.w - mu) * rstd * gs[c+3] + bs[c+3];
        xn[r][c+4] = (b.x - mu) * rstd * gs[c+4] + bs[c+4];
        xn[r][c+5] = (b.y - mu) * rstd * gs[c+5] + bs[c+5];
        xn[r][c+6] = (b.z - mu) * rstd * gs[c+6] + bs[c+6];
        xn[r][c+7] = (b.w - mu) * rstd * gs[c+7] + bs[c+7];
    }
    __syncthreads();

    const int c0 = (t & 63) * 6;
    const int r0 = (t >> 6) * 8;
    float acc[8][6];
    #pragma unroll
    for (int i = 0; i < 8; ++i)
        #pragma unroll
        for (int j = 0; j < 6; ++j) acc[i][j] = 0.0f;

    #pragma unroll 4
    for (int kk = 0; kk < 512; ++kk) {
        const float* wrow = wqkv + (size_t)kk * W3 + c0;
        const float w0 = wrow[0], w1 = wrow[1], w2 = wrow[2];
        const float w3 = wrow[3], w4 = wrow[4], w5 = wrow[5];
        #pragma unroll
        for (int i = 0; i < 8; ++i) {
            const float xv = xn[r0+i][kk];
            acc[i][0] = fmaf(xv, w0, acc[i][0]);
            acc[i][1] = fmaf(xv, w1, acc[i][1]);
            acc[i][2] = fmaf(xv, w2, acc[i][2]);
            acc[i][3] = fmaf(xv, w3, acc[i][3]);
            acc[i][4] = fmaf(xv, w4, acc[i][4]);
            acc[i][5] = fmaf(xv, w5, acc[i][5]);
        }
    }

    #pragma unroll
    for (int i = 0; i < 8; ++i) {
        const int grow = row0 + r0 + i;
        const int b = grow >> 13;
        const int n = grow & (NSEQ - 1);
        #pragma unroll
        for (int j = 0; j < 6; ++j) {
            const int c = c0 + j;
            const float val = acc[i][j];
            if (c < INNER) {
                const int h = c >> 6, d = c & 63;
                q[(((size_t)b*HH + h)*NSEQ + n)*DH + d] = val * 0.125f;
            } else if (c < 2*INNER) {
                const int cc = c - INNER;
                const int h = cc >> 6, d = cc & 63;
                k[(((size_t)b*HH + h)*NSEQ + n)*DH + d] = val;
            } else {
                const int cc = c - 2*INNER;
                const int h = cc >> 6, d = cc & 63;
                v[(((size_t)b*HH + h)*NSEQ + n)*DH + d] = val;
            }
        }
    }
}

// ---------------------------------------------------------------------------
// K2: landmark means over chunks of 32 rows.
// ---------------------------------------------------------------------------
__global__ __launch_bounds__(256) void landmark_kernel(
    const float* __restrict__ q, const float* __restrict__ k,
    float* __restrict__ ql, float* __restrict__ kl)
{
    const int t = threadIdx.x;
    const int g = blockIdx.x * 4 + (t >> 6);
    const int d = t & 63;
    const int bh = g >> 8;
    const int m  = g & 255;
    const float* qb = q + ((size_t)bh * NSEQ + (size_t)m * LCH) * DH + d;
    const float* kb = k + ((size_t)bh * NSEQ + (size_t)m * LCH) * DH + d;
    float sq = 0.0f, sk = 0.0f;
    #pragma unroll
    for (int i = 0; i < LCH; ++i) { sq += qb[i*DH]; sk += kb[i*DH]; }
    ql[((size_t)bh * MLAND + m) * DH + d] = sq * (1.0f/LCH);
    kl[((size_t)bh * MLAND + m) * DH + d] = sk * (1.0f/LCH);
}

// ---------------------------------------------------------------------------
// K3: a2 = softmax(q_l @ k_l^T).
// ---------------------------------------------------------------------------
__global__ __launch_bounds__(256) void sim2_kernel(
    const float* __restrict__ ql, const float* __restrict__ kl,
    float* __restrict__ a2)
{
    const int bh = blockIdx.x >> 8;
    const int i  = blockIdx.x & 255;
    const int j  = threadIdx.x;
    __shared__ float qrow[64];
    __shared__ float red[8];
    if (j < 64) qrow[j] = ql[((size_t)bh*MLAND + i)*DH + j];
    __syncthreads();
    const float4* k4 = (const float4*)(kl + ((size_t)bh*MLAND + j)*DH);
    float s = 0.0f;
    #pragma unroll
    for (int u = 0; u < 16; ++u) {
        const float4 kv = k4[u];
        s = fmaf(qrow[u*4+0], kv.x, s);
        s = fmaf(qrow[u*4+1], kv.y, s);
        s = fmaf(qrow[u*4+2], kv.z, s);
        s = fmaf(qrow[u*4+3], kv.w, s);
    }
    float m = s;
    #pragma unroll
    for (int o = 32; o > 0; o >>= 1) m = fmaxf(m, __shfl_xor(m, o, 64));
    if ((j & 63) == 0) red[j >> 6] = m;
    __syncthreads();
    m = fmaxf(fmaxf(red[0], red[1]), fmaxf(red[2], red[3]));
    const float e = __expf(s - m);
    float l = e;
    #pragma unroll
    for (int o = 32; o > 0; o >>= 1) l += __shfl_xor(l, o, 64);
    if ((j & 63) == 0) red[4 + (j >> 6)] = l;
    __syncthreads();
    l = red[4] + red[5] + red[6] + red[7];
    a2[((size_t)bh*MLAND + i)*MLAND + j] = e / l;
}

// ---------------------------------------------------------------------------
// K4: pinv init.
// ---------------------------------------------------------------------------
__global__ void initmax_kernel(unsigned int* mx) {
    if (threadIdx.x < 2) mx[threadIdx.x] = 0u;
}

__global__ __launch_bounds__(256) void pinv_sums_kernel(
    const float* __restrict__ a2, unsigned int* __restrict__ mx)
{
    const int bh = blockIdx.x;
    const int t = threadIdx.x;
    const float* A = a2 + (size_t)bh * MLAND * MLAND;
    float rs = 0.0f, cs = 0.0f;
    const float4* row4 = (const float4*)(A + (size_t)t * MLAND);
    #pragma unroll 8
    for (int u = 0; u < 64; ++u) {
        const float4 val = row4[u];
        rs += fabsf(val.x) + fabsf(val.y) + fabsf(val.z) + fabsf(val.w);
    }
    #pragma unroll 8
    for (int i = 0; i < MLAND; ++i) cs += fabsf(A[(size_t)i*MLAND + t]);
    __shared__ float red[8];
    float mrs = rs, mcs = cs;
    #pragma unroll
    for (int o = 32; o > 0; o >>= 1) {
        mrs = fmaxf(mrs, __shfl_xor(mrs, o, 64));
        mcs = fmaxf(mcs, __shfl_xor(mcs, o, 64));
    }
    if ((t & 63) == 0) { red[t>>6] = mrs; red[4+(t>>6)] = mcs; }
    __syncthreads();
    if (t == 0) {
        const float a = fmaxf(fmaxf(red[0],red[1]), fmaxf(red[2],red[3]));
        const float b = fmaxf(fmaxf(red[4],red[5]), fmaxf(red[6],red[7]));
        atomicMax(&mx[0], __float_as_uint(a));
        atomicMax(&mx[1], __float_as_uint(b));
    }
}

__global__ __launch_bounds__(256) void z0_kernel(
    const float* __restrict__ a2, const unsigned int* __restrict__ mx,
    float* __restrict__ z)
{
    const float scale = 1.0f / (__uint_as_float(mx[0]) * __uint_as_float(mx[1]));
    const size_t idx = (size_t)blockIdx.x * 256 + threadIdx.x;
    const size_t bh = idx >> 16;
    const size_t i = (idx >> 8) & 255;
    const size_t j = idx & 255;
    z[idx] = a2[(bh << 16) | (j << 8) | i] * scale;
}

// ---------------------------------------------------------------------------
// K5: batched (8x) 256x256 @ 256xNC:  C = c1*A + c2*(A@B).
// ---------------------------------------------------------------------------
__global__ __launch_bounds__(256) void mm256_kernel(
    float* __restrict__ C, const float* __restrict__ A,
    const float* __restrict__ Bm, float c1, float c2, int NC)
{
    __shared__ float As[32][65];
    __shared__ float Bs[64][68];
    const int bh = blockIdx.z;
    const int row0 = blockIdx.y * 32;
    const int col0 = blockIdx.x * 64;
    const float* Ab = A + (size_t)bh * MLAND * MLAND;
    const float* Bb = Bm + (size_t)bh * MLAND * NC;
    const int t = threadIdx.x;
    const int tc = (t & 15) * 4;
    const int tr = (t >> 4) * 2;
    float acc[2][4] = {{0,0,0,0},{0,0,0,0}};
    for (int k0 = 0; k0 < 256; k0 += 64) {
        #pragma unroll
        for (int u = 0; u < 2; ++u) {
            const int idx = t + u*256;
            const int r = idx >> 4, c4 = (idx & 15) * 4;
            const float4 val = *(const float4*)(Ab + (size_t)(row0 + r) * MLAND + k0 + c4);
            As[r][c4+0] = val.x; As[r][c4+1] = val.y;
            As[r][c4+2] = val.z; As[r][c4+3] = val.w;
        }
        #pragma unroll
        for (int u = 0; u < 4; ++u) {
            const int idx = t + u*256;
            const int r = idx >> 4, c4 = (idx & 15) * 4;
            *(float4*)&Bs[r][c4] = *(const float4*)(Bb + (size_t)(k0 + r) * NC + col0 + c4);
        }
        __syncthreads();
        #pragma unroll 8
        for (int kk = 0; kk < 64; ++kk) {
            const float a0 = As[tr][kk];
            const float a1 = As[tr+1][kk];
            const float4 b4 = *(const float4*)&Bs[kk][tc];
            acc[0][0] = fmaf(a0, b4.x, acc[0][0]);
            acc[0][1] = fmaf(a0, b4.y, acc[0][1]);
            acc[0][2] = fmaf(a0, b4.z, acc[0][2]);
            acc[0][3] = fmaf(a0, b4.w, acc[0][3]);
            acc[1][0] = fmaf(a1, b4.x, acc[1][0]);
            acc[1][1] = fmaf(a1, b4.y, acc[1][1]);
            acc[1][2] = fmaf(a1, b4.z, acc[1][2]);
            acc[1][3] = fmaf(a1, b4.w, acc[1][3]);
        }
        __syncthreads();
    }
    #pragma unroll
    for (int i = 0; i < 2; ++i) {
        const int r = row0 + tr + i;
        #pragma unroll
        for (int j = 0; j < 4; ++j) {
            const int c = col0 + tc + j;
            float val = c2 * acc[i][j];
            if (c1 != 0.0f) val = fmaf(c1, Ab[(size_t)r * MLAND + c], val);
            C[((size_t)bh * MLAND + r) * NC + c] = val;
        }
    }
}

// ---------------------------------------------------------------------------
// K6: flash-style a3v partials.
// ---------------------------------------------------------------------------
__global__ __launch_bounds__(256, 1) void sim3_kernel(
    const float* __restrict__ ql, const float* __restrict__ kg,
    const float* __restrict__ vg, float* __restrict__ po,
    float* __restrict__ pm, float* __restrict__ pl)
{
    __shared__ float ks[64][68];
    __shared__ float vs[64][68];
    const int ch = blockIdx.x;
    const int bh = blockIdx.y;
    const int t = threadIdx.x;
    float4 q4[16];
    {
        const float* qr = ql + ((size_t)bh * MLAND + t) * DH;
        #pragma unroll
        for (int u = 0; u < 16; ++u) q4[u] = *(const float4*)(qr + u*4);
    }
    float4 o4[16];
    #pragma unroll
    for (int u = 0; u < 16; ++u) o4[u] = make_float4(0.f,0.f,0.f,0.f);
    float m = -1e30f, l = 0.0f;

    #pragma unroll 1
    for (int sc = 0; sc < 4; ++sc) {
        const int j0 = ch * 256 + sc * 64;
        #pragma unroll
        for (int u = 0; u < 4; ++u) {
            const int idx = t + u*256;
            const int r = idx >> 4, c4 = (idx & 15) * 4;
            *(float4*)&ks[r][c4] = *(const float4*)(kg + ((size_t)bh*NSEQ + j0 + r)*DH + c4);
            *(float4*)&vs[r][c4] = *(const float4*)(vg + ((size_t)bh*NSEQ + j0 + r)*DH + c4);
        }
        __syncthreads();
        #pragma unroll 1
        for (int b16 = 0; b16 < 4; ++b16) {
            float s[16];
            #pragma unroll
            for (int c = 0; c < 16; ++c) {
                const int cc = b16*16 + c;
                float a = 0.0f;
                #pragma unroll
                for (int u = 0; u < 16; ++u) {
                    const float4 kv = *(const float4*)&ks[cc][u*4];
                    a = fmaf(q4[u].x, kv.x, a);
                    a = fmaf(q4[u].y, kv.y, a);
                    a = fmaf(q4[u].z, kv.z, a);
                    a = fmaf(q4[u].w, kv.w, a);
                }
                s[c] = a;
            }
            float bm = s[0];
            #pragma unroll
            for (int c = 1; c < 16; ++c) bm = fmaxf(bm, s[c]);
            const float mn = fmaxf(m, bm);
            const float scale = __expf(m - mn);
            l *= scale;
            #pragma unroll
            for (int u = 0; u < 16; ++u) {
                o4[u].x *= scale; o4[u].y *= scale;
                o4[u].z *= scale; o4[u].w *= scale;
            }
            #pragma unroll
            for (int c = 0; c < 16; ++c) {
                const int cc = b16*16 + c;
                const float p = __expf(s[c] - mn);
                l += p;
                #pragma unroll
                for (int u = 0; u < 16; ++u) {
                    const float4 vv = *(const float4*)&vs[cc][u*4];
                    o4[u].x = fmaf(p, vv.x, o4[u].x);
                    o4[u].y = fmaf(p, vv.y, o4[u].y);
                    o4[u].z = fmaf(p, vv.z, o4[u].z);
                    o4[u].w = fmaf(p, vv.w, o4[u].w);
                }
            }
            m = mn;
        }
        __syncthreads();
    }
    float* od = po + (((size_t)bh*32 + ch) * MLAND + t) * DH;
    #pragma unroll
    for (int u = 0; u < 16; ++u) *(float4*)(od + u*4) = o4[u];
    pm[((size_t)bh*32 + ch) * MLAND + t] = m;
    pl[((size_t)bh*32 + ch) * MLAND + t] = l;
}

// K7: merge 32 chunk partials -> a3v
__global__ __launch_bounds__(256) void sim3red_kernel(
    const float* __restrict__ po, const float* __restrict__ pm,
    const float* __restrict__ pl, float* __restrict__ a3v)
{
    const int g = blockIdx.x * 4 + (threadIdx.x >> 6);
    const int d = threadIdx.x & 63;
    const int bh = g >> 8;
    const int r = g & 255;
    float M = -1e30f;
    #pragma unroll
    for (int c = 0; c < 32; ++c)
        M = fmaxf(M, pm[((size_t)bh*32 + c)*MLAND + r]);
    float L = 0.0f, o = 0.0f;
    #pragma unroll 1
    for (int c = 0; c < 32; ++c) {
        const float w = __expf(pm[((size_t)bh*32 + c)*MLAND + r] - M);
        L = fmaf(pl[((size_t)bh*32 + c)*MLAND + r], w, L);
        o = fmaf(po[(((size_t)bh*32 + c)*MLAND + r)*DH + d], w, o);
    }
    a3v[((size_t)bh*MLAND + r)*DH + d] = o / L;
}

// ---------------------------------------------------------------------------
// K8a: convert kl (fp32 [bh][256][64]) -> bf16 klb, same layout.
// ---------------------------------------------------------------------------
__global__ __launch_bounds__(256) void packkl_kernel(
    const float* __restrict__ klm, short* __restrict__ klb)
{
    const int idx = blockIdx.x * 256 + threadIdx.x;
    klb[idx] = f2bf(klm[idx]);
}

// K8b: convert + transpose W (fp32 [bh][256][64]) -> bf16 Wt [bh][64][256].
__global__ __launch_bounds__(256) void packwt_kernel(
    const float* __restrict__ Wm, short* __restrict__ wtb)
{
    const int idx = blockIdx.x * 256 + threadIdx.x;
    const int bh = idx >> 14;
    const int rem = idx & 16383;
    const int d = rem >> 8;
    const int m = rem & 255;
    wtb[idx] = f2bf(Wm[((size_t)bh * MLAND + m) * DH + d]);
}

// ---------------------------------------------------------------------------
// K8: MFMA flash attention vs 256 landmarks.
// Block: 4 waves x 16 q-rows = 64 rows, one bh. LDS: kl 32KB (overlaid by
// P^T after QK phase) + Wt 32KB = 64KB -> 2 blocks/CU.
// S^T = kl @ q^T via mfma_16x16x32_bf16 (D: row=m=(lg*4+j)+16*mt, col=r=lr).
// Softmax over m: in-reg + shfl_xor(16,32). P^T -> swizzled LDS.
// O^T = Wt @ P^T; store O[r][d]/l_r to inner.
// XOR swizzle everywhere: 16B-slot index ^= (row&7).
// ---------------------------------------------------------------------------
__global__ __launch_bounds__(256, 2) void final1_mfma_kernel(
    const float* __restrict__ q, const short* __restrict__ klb,
    const short* __restrict__ wtb, float* __restrict__ inner)
{
    __shared__ short ldsA[16384];   // 32KB: kl (phase1) / P^T (phase2)
    __shared__ short ldsW[16384];   // 32KB: Wt, rows d, 256 shorts each
    const int bh = blockIdx.y;
    const int b = bh >> 1;
    const int h = bh & 1;
    const int t = threadIdx.x;
    const int w = t >> 6;
    const int l = t & 63;
    const int lr = l & 15;
    const int lg = l >> 4;

    // stage klb [m][64] and Wt [d][256] with slot-XOR swizzle
    {
        const short* klsrc = klb + (size_t)bh * 16384;
        const short* wtsrc = wtb + (size_t)bh * 16384;
        #pragma unroll
        for (int u = 0; u < 8; ++u) {
            const int gi = t + u * 256;          // 0..2047 granules of 8 shorts
            const int m  = gi >> 3, sl = gi & 7;
            *(short8v*)&ldsA[m*64 + (sl ^ (m & 7))*8] =
                *(const short8v*)(klsrc + gi*8);
            const int dd = gi >> 5, sw = gi & 31;
            *(short8v*)&ldsW[dd*256 + (sw ^ (dd & 7))*8] =
                *(const short8v*)(wtsrc + gi*8);
        }
    }
    __syncthreads();

    // q B-fragments (fp32 global -> bf16): col r=lr -> row n; k: d=kh*32+lg*8
    const int n = blockIdx.x * 64 + w * 16 + lr;
    short8v qb0, qb1;
    {
        const float* qr = q + ((size_t)bh * NSEQ + n) * DH + lg * 8;
        const float4 f0 = *(const float4*)qr;
        const float4 f1 = *(const float4*)(qr + 4);
        const float4 f2 = *(const float4*)(qr + 32);
        const float4 f3 = *(const float4*)(qr + 36);
        qb0[0]=f2bf(f0.x); qb0[1]=f2bf(f0.y); qb0[2]=f2bf(f0.z); qb0[3]=f2bf(f0.w);
        qb0[4]=f2bf(f1.x); qb0[5]=f2bf(f1.y); qb0[6]=f2bf(f1.z); qb0[7]=f2bf(f1.w);
        qb1[0]=f2bf(f2.x); qb1[1]=f2bf(f2.y); qb1[2]=f2bf(f2.z); qb1[3]=f2bf(f2.w);
        qb1[4]=f2bf(f3.x); qb1[5]=f2bf(f3.y); qb1[6]=f2bf(f3.z); qb1[7]=f2bf(f3.w);
    }

    // QK^T (swapped): S^T[m][r], 16 m-tiles
    f32x4 accS[16];
    #pragma unroll
    for (int mt = 0; mt < 16; ++mt) accS[mt] = (f32x4){0.f,0.f,0.f,0.f};
    const int s8 = lr & 7;
    #pragma unroll
    for (int mt = 0; mt < 16; ++mt) {
        const int m = mt * 16 + lr;
        const short8v a0 = *(const short8v*)&ldsA[m*64 + ((0*4 + lg) ^ s8)*8];
        const short8v a1 = *(const short8v*)&ldsA[m*64 + ((1*4 + lg) ^ s8)*8];
        accS[mt] = __builtin_amdgcn_mfma_f32_16x16x32_bf16(a0, qb0, accS[mt], 0, 0, 0);
        accS[mt] = __builtin_amdgcn_mfma_f32_16x16x32_bf16(a1, qb1, accS[mt], 0, 0, 0);
    }

    // softmax over m (rows of S^T = landmark index); col r is lane-local
    float mloc = -1e30f;
    #pragma unroll
    for (int mt = 0; mt < 16; ++mt)
        #pragma unroll
        for (int j = 0; j < 4; ++j) mloc = fmaxf(mloc, accS[mt][j]);
    mloc = fmaxf(mloc, __shfl_xor(mloc, 16, 64));
    mloc = fmaxf(mloc, __shfl_xor(mloc, 32, 64));
    float lsum = 0.0f;
    #pragma unroll
    for (int mt = 0; mt < 16; ++mt)
        #pragma unroll
        for (int j = 0; j < 4; ++j) {
            const float p = __expf(accS[mt][j] - mloc);
            accS[mt][j] = p;
            lsum += p;
        }
    lsum += __shfl_xor(lsum, 16, 64);
    lsum += __shfl_xor(lsum, 32, 64);

    __syncthreads();   // all waves done reading kl -> safe to overlay with P^T

    // write P^T (bf16) to wave-private region: row r (16 rows x 512B), swizzled
    {
        short* pw = ldsA + w * 4096;
        #pragma unroll
        for (int mt = 0; mt < 16; ++mt) {
            short4v pk;
            pk[0] = f2bf(accS[mt][0]); pk[1] = f2bf(accS[mt][1]);
            pk[2] = f2bf(accS[mt][2]); pk[3] = f2bf(accS[mt][3]);
            const int byteoff = (mt*32 + lg*8) ^ (s8 << 4);
            *(short4v*)&pw[lr*256 + (byteoff >> 1)] = pk;
        }
    }
    __syncthreads();

    // PV: O^T[d][r] = Wt @ P^T
    short8v pb[8];
    {
        const short* pw = ldsA + w * 4096;
        #pragma unroll
        for (int kc = 0; kc < 8; ++kc) {
            const int byteoff = (kc*64 + lg*16) ^ (s8 << 4);
            pb[kc] = *(const short8v*)&pw[lr*256 + (byteoff >> 1)];
        }
    }
    f32x4 accO[4];
    #pragma unroll
    for (int dt = 0; dt < 4; ++dt) accO[dt] = (f32x4){0.f,0.f,0.f,0.f};
    #pragma unroll
    for (int dt = 0; dt < 4; ++dt) {
        const int d = dt * 16 + lr;
        #pragma unroll
        for (int kc = 0; kc < 8; ++kc) {
            const short8v wa = *(const short8v*)&ldsW[d*256 + (((kc*64 + lg*16) ^ (s8 << 4)) >> 1)];
            accO[dt] = __builtin_amdgcn_mfma_f32_16x16x32_bf16(wa, pb[kc], accO[dt], 0, 0, 0);
        }
    }

    // store O[r][d] / l_r
    const float rl = 1.0f / lsum;
    float* ob = inner + ((size_t)b * NSEQ + n) * INNER + h * DH + lg * 4;
    #pragma unroll
    for (int dt = 0; dt < 4; ++dt) {
        float4 o;
        o.x = accO[dt][0] * rl; o.y = accO[dt][1] * rl;
        o.z = accO[dt][2] * rl; o.w = accO[dt][3] * rl;
        *(float4*)(ob + dt * 16) = o;
    }
}

// ---------------------------------------------------------------------------
// K9: depthwise conv-33 residual: inner[b][n][h*64+d] += conv(v).
// ---------------------------------------------------------------------------
__global__ __launch_bounds__(256) void conv_add_kernel(
    const float* __restrict__ vg, const float* __restrict__ wres,
    float* __restrict__ inner)
{
    __shared__ float wr[KER];
    const int bh = blockIdx.y;
    const int b = bh >> 1;
    const int h = bh & 1;
    const int t = threadIdx.x;
    if (t < KER) wr[t] = wres[h*KER + t];
    __syncthreads();
    const int d = t & 63;
    const int g = t >> 6;
    const int n0 = blockIdx.x * 128;
    #pragma unroll 1
    for (int i = 0; i < 32; ++i) {
        const int n = n0 + g + i*4;
        float acc = 0.0f;
        #pragma unroll
        for (int tt = 0; tt < KER; ++tt) {
            const int nn = n - 16 + tt;
            if (nn >= 0 && nn < NSEQ)
                acc = fmaf(vg[((size_t)bh*NSEQ + nn)*DH + d], wr[tt], acc);
        }
        const size_t idx = ((size_t)b*NSEQ + n)*INNER + h*DH + d;
        inner[idx] += acc;
    }
}

// K10: out = inner @ w_out + b_out + x.
__global__ __launch_bounds__(256) void final2_kernel(
    const float* __restrict__ inner, const float* __restrict__ wout,
    const float* __restrict__ bout, const float* __restrict__ x,
    float* __restrict__ out)
{
    __shared__ float is[32][129];
    const int t = threadIdx.x;
    const size_t row0 = (size_t)blockIdx.x * 32;
    #pragma unroll
    for (int u = 0; u < 4; ++u) {
        const int idx = t + u*256;
        const int r = idx >> 5, c4 = (idx & 31) * 4;
        const float4 val = *(const float4*)(inner + (row0 + r)*INNER + c4);
        is[r][c4+0]=val.x; is[r][c4+1]=val.y; is[r][c4+2]=val.z; is[r][c4+3]=val.w;
    }
    __syncthreads();
    const int c0 = (t & 63) * 8;
    const int r0 = (t >> 6) * 8;
    float acc[8][8];
    #pragma unroll
    for (int i = 0; i < 8; ++i)
        #pragma unroll
        for (int j = 0; j < 8; ++j) acc[i][j] = 0.0f;
    #pragma unroll 2
    for (int kk = 0; kk < 128; ++kk) {
        const float4 w0 = *(const float4*)(wout + (size_t)kk*DMODEL + c0);
        const float4 w1 = *(const float4*)(wout + (size_t)kk*DMODEL + c0 + 4);
        #pragma unroll
        for (int i = 0; i < 8; ++i) {
            const float xv = is[r0+i][kk];
            acc[i][0] = fmaf(xv, w0.x, acc[i][0]);
            acc[i][1] = fmaf(xv, w0.y, acc[i][1]);
            acc[i][2] = fmaf(xv, w0.z, acc[i][2]);
            acc[i][3] = fmaf(xv, w0.w, acc[i][3]);
            acc[i][4] = fmaf(xv, w1.x, acc[i][4]);
            acc[i][5] = fmaf(xv, w1.y, acc[i][5]);
            acc[i][6] = fmaf(xv, w1.z, acc[i][6]);
            acc[i][7] = fmaf(xv, w1.w, acc[i][7]);
        }
    }
    const float4 b0 = *(const float4*)(bout + c0);
    const float4 b1 = *(const float4*)(bout + c0 + 4);
    #pragma unroll
    for (int i = 0; i < 8; ++i) {
        const size_t row = row0 + r0 + i;
        const float4 x0 = *(const float4*)(x + row*DMODEL + c0);
        const float4 x1 = *(const float4*)(x + row*DMODEL + c0 + 4);
        float4 o0, o1;
        o0.x = acc[i][0] + b0.x + x0.x;
        o0.y = acc[i][1] + b0.y + x0.y;
        o0.z = acc[i][2] + b0.z + x0.z;
        o0.w = acc[i][3] + b0.w + x0.w;
        o1.x = acc[i][4] + b1.x + x1.x;
        o1.y = acc[i][5] + b1.y + x1.y;
        o1.z = acc[i][6] + b1.z + x1.z;
        o1.w = acc[i][7] + b1.w + x1.w;
        *(float4*)(out + row*DMODEL + c0) = o0;
        *(float4*)(out + row*DMODEL + c0 + 4) = o1;
    }
}

// ---------------------------------------------------------------------------
extern "C" void kernel_launch(void* const* d_in, const int* in_sizes, int n_in,
                              void* d_out, int out_size, void* d_ws, size_t ws_size,
                              hipStream_t stream)
{
    const float* x     = (const float*)d_in[0];
    const float* gamma = (const float*)d_in[1];
    const float* beta  = (const float*)d_in[2];
    const float* wqkv  = (const float*)d_in[3];
    const float* wout  = (const float*)d_in[4];
    const float* bout  = (const float*)d_in[5];
    const float* wres  = (const float*)d_in[6];
    float* out = (float*)d_out;

    float* ws = (float*)d_ws;
    const size_t QS = (size_t)BH * NSEQ * DH;       // 4194304
    const size_t LS = (size_t)BH * MLAND * DH;      // 131072
    const size_t MS = (size_t)BH * MLAND * MLAND;   // 524288
    float* q    = ws;
    float* kbuf = q + QS;
    float* vbuf = kbuf + QS;
    float* ql   = vbuf + QS;
    float* klm  = ql + LS;
    float* a2   = klm + LS;
    float* zA   = a2 + MS;
    float* zB   = zA + MS;
    float* xz   = zB + MS;
    float* t1   = xz + MS;
    float* t2   = t1 + MS;
    float* a3v  = t2 + MS;
    float* Wm   = a3v + LS;
    float* po   = Wm + LS;
    float* pm   = po + QS;
    float* pl   = pm + (size_t)BH * 32 * MLAND;
    unsigned int* mx = (unsigned int*)(pl + (size_t)BH * 32 * MLAND);
    float* inner = po;            // po dead after sim3red
    // bf16 buffers carved from kbuf (k dead after sim3)
    short* klb = (short*)kbuf;            // BH*256*64 bf16
    short* wtb = (short*)kbuf + LS;       // BH*64*256 bf16 (transposed W)

    ln_qkv_kernel<<<(BB*NSEQ)/32, 256, 0, stream>>>(x, gamma, beta, wqkv, q, kbuf, vbuf);
    landmark_kernel<<<(BH*MLAND)/4, 256, 0, stream>>>(q, kbuf, ql, klm);
    sim2_kernel<<<BH*MLAND, 256, 0, stream>>>(ql, klm, a2);

    // a3v (uses kbuf/vbuf; after this kbuf is dead)
    sim3_kernel<<<dim3(32, BH), 256, 0, stream>>>(ql, kbuf, vbuf, po, pm, pl);
    sim3red_kernel<<<(BH*MLAND)/4, 256, 0, stream>>>(po, pm, pl, a3v);

    // pinv of a2 (6 Newton iterations, fp32)
    initmax_kernel<<<1, 64, 0, stream>>>(mx);
    pinv_sums_kernel<<<BH, 256, 0, stream>>>(a2, mx);
    z0_kernel<<<(unsigned)(MS/256), 256, 0, stream>>>(a2, mx, zA);
    float* za = zA;
    float* zb = zB;
    for (int it = 0; it < 6; ++it) {
        mm256_kernel<<<dim3(4,8,BH), 256, 0, stream>>>(xz, a2, za, 0.0f, 1.0f, 256);
        mm256_kernel<<<dim3(4,8,BH), 256, 0, stream>>>(t1, xz, xz, 7.0f, -1.0f, 256);
        mm256_kernel<<<dim3(4,8,BH), 256, 0, stream>>>(t2, xz, t1, 15.0f, -1.0f, 256);
        mm256_kernel<<<dim3(4,8,BH), 256, 0, stream>>>(zb, za, t2, 3.25f, -0.25f, 256);
        float* tmp = za; za = zb; zb = tmp;
    }
    // W = a2_inv @ a3v
    mm256_kernel<<<dim3(1,8,BH), 256, 0, stream>>>(Wm, za, a3v, 0.0f, 1.0f, 64);

    // bf16 packs (into dead kbuf region)
    packkl_kernel<<<(unsigned)(LS/256), 256, 0, stream>>>(klm, klb);
    packwt_kernel<<<(unsigned)(LS/256), 256, 0, stream>>>(Wm, wtb);

    final1_mfma_kernel<<<dim3(NSEQ/64, BH), 256, 0, stream>>>(q, klb, wtb, inner);
    conv_add_kernel<<<dim3(NSEQ/128, BH), 256, 0, stream>>>(vbuf, wres, inner);
    final2_kernel<<<(BB*NSEQ)/32, 256, 0, stream>>>(inner, wout, bout, x, out);
}

// Round 4
// 989.899 us; speedup vs baseline: 1.5234x; 1.1403x over previous
//
#include <hip/hip_runtime.h>
#include <math.h>

// ---------------------------------------------------------------------------
// Nystromformer layer, round 4:
//  - ln_qkv -> bf16 MFMA (wqkv pre-packed to fragment order, global_load_lds)
//  - final2 -> bf16 MFMA (wout packed to fragment order, direct-from-L2 B)
//  - pinv: proven 25-launch fp32 mm256 chain (coop launch removed to de-risk
//    after round-3 container failure)
// ---------------------------------------------------------------------------

#define BB 4
#define HH 2
#define NSEQ 8192
#define DMODEL 512
#define DH 64
#define MLAND 256
#define LCH 32
#define W3 384
#define INNER 128
#define KER 33
#define BH (BB*HH)

typedef __attribute__((ext_vector_type(8))) short short8v;
typedef __attribute__((ext_vector_type(4))) short short4v;
typedef __attribute__((ext_vector_type(4))) float f32x4;

__device__ __forceinline__ short f2bf(float f) {
    unsigned u = __float_as_uint(f);
    u = (u + 0x7FFFu + ((u >> 16) & 1u)) >> 16;
    return (short)u;
}

__device__ __forceinline__ void gload_lds16(const short* g, short* l) {
    __builtin_amdgcn_global_load_lds(
        (const __attribute__((address_space(1))) unsigned int*)(g),
        (__attribute__((address_space(3))) unsigned int*)(l), 16, 0, 0);
}

// ---------------------------------------------------------------------------
// Pack wqkv [512][384] fp32 -> bf16 fragment order:
// frag idx = (ks*24 + ct)*64 + l ; element j: k = ks*32+(l>>4)*8+j, c = ct*16+(l&15)
// ---------------------------------------------------------------------------
__global__ __launch_bounds__(256) void pack_wqkv_kernel(
    const float* __restrict__ w, short* __restrict__ wf)
{
    const int idx = blockIdx.x * 256 + threadIdx.x;   // 0..24575
    const int l = idx & 63;
    const int ct = (idx >> 6) % 24;
    const int ks = idx / 1536;
    const int c = ct * 16 + (l & 15);
    const int k0 = ks * 32 + (l >> 4) * 8;
    short8v o;
    #pragma unroll
    for (int j = 0; j < 8; ++j) o[j] = f2bf(w[(size_t)(k0 + j) * W3 + c]);
    *(short8v*)&wf[(size_t)idx * 8] = o;
}

// Pack wout [128][512] fp32 -> bf16 fragment order (4 ks x 32 ct).
__global__ __launch_bounds__(256) void pack_wout_kernel(
    const float* __restrict__ w, short* __restrict__ wf)
{
    const int idx = blockIdx.x * 256 + threadIdx.x;   // 0..8191
    const int l = idx & 63;
    const int ct = (idx >> 6) & 31;
    const int ks = idx >> 11;
    const int c = ct * 16 + (l & 15);
    const int k0 = ks * 32 + (l >> 4) * 8;
    short8v o;
    #pragma unroll
    for (int j = 0; j < 8; ++j) o[j] = f2bf(w[(size_t)(k0 + j) * DMODEL + c]);
    *(short8v*)&wf[(size_t)idx * 8] = o;
}

// Pack inner fp32 -> bf16 (same layout).
__global__ __launch_bounds__(256) void pack_inner_kernel(
    const float* __restrict__ in, short* __restrict__ o)
{
    const size_t i8 = (size_t)blockIdx.x * 256 + threadIdx.x;  // 0..524287
    const float4 a = *(const float4*)(in + i8 * 8);
    const float4 b = *(const float4*)(in + i8 * 8 + 4);
    short8v s;
    s[0]=f2bf(a.x); s[1]=f2bf(a.y); s[2]=f2bf(a.z); s[3]=f2bf(a.w);
    s[4]=f2bf(b.x); s[5]=f2bf(b.y); s[6]=f2bf(b.z); s[7]=f2bf(b.w);
    *(short8v*)&o[i8 * 8] = s;
}

// ---------------------------------------------------------------------------
// K1: fused LayerNorm + QKV GEMM, bf16 MFMA. 64 rows/block, 512 blocks.
// xn (bf16, XOR-swizzled) in LDS; W staged per K-step via global_load_lds
// from fragment-ordered wfrag (double-buffered). q scaled by DH^-0.5.
// ---------------------------------------------------------------------------
__global__ __launch_bounds__(256, 1) void ln_qkv_mfma_kernel(
    const float* __restrict__ x, const float* __restrict__ gamma,
    const float* __restrict__ beta, const short* __restrict__ wfrag,
    float* __restrict__ q, float* __restrict__ k, float* __restrict__ v)
{
    __shared__ short xn[64 * 512];      // 64KB, swizzled: slot = (k>>3)^(r&7)
    __shared__ short bsh[2 * 12288];    // 48KB, B double buffer (frag order)
    __shared__ float gs[512];
    __shared__ float bs2[512];
    const int t = threadIdx.x;
    const int w = t >> 6;
    const int lane = t & 63;
    const int row0 = blockIdx.x * 64;

    for (int i = t; i < 512; i += 256) { gs[i] = gamma[i]; bs2[i] = beta[i]; }
    __syncthreads();

    // LN: wave w handles rows 16w..16w+15
    #pragma unroll 1
    for (int i = 0; i < 16; ++i) {
        const int r = w * 16 + i;
        const float* xr = x + ((size_t)row0 + r) * DMODEL + lane * 8;
        const float4 a = *(const float4*)(xr);
        const float4 b = *(const float4*)(xr + 4);
        float s  = a.x + a.y + a.z + a.w + b.x + b.y + b.z + b.w;
        float ss = a.x*a.x + a.y*a.y + a.z*a.z + a.w*a.w
                 + b.x*b.x + b.y*b.y + b.z*b.z + b.w*b.w;
        #pragma unroll
        for (int o = 32; o > 0; o >>= 1) {
            s  += __shfl_xor(s, o, 64);
            ss += __shfl_xor(ss, o, 64);
        }
        const float mu = s * (1.0f/512.0f);
        const float var = ss * (1.0f/512.0f) - mu*mu;
        const float rstd = rsqrtf(var + 1e-5f);
        const int c = lane * 8;
        short8v o8;
        o8[0] = f2bf((a.x - mu) * rstd * gs[c+0] + bs2[c+0]);
        o8[1] = f2bf((a.y - mu) * rstd * gs[c+1] + bs2[c+1]);
        o8[2] = f2bf((a.z - mu) * rstd * gs[c+2] + bs2[c+2]);
        o8[3] = f2bf((a.w - mu) * rstd * gs[c+3] + bs2[c+3]);
        o8[4] = f2bf((b.x - mu) * rstd * gs[c+4] + bs2[c+4]);
        o8[5] = f2bf((b.y - mu) * rstd * gs[c+5] + bs2[c+5]);
        o8[6] = f2bf((b.z - mu) * rstd * gs[c+6] + bs2[c+6]);
        o8[7] = f2bf((b.w - mu) * rstd * gs[c+7] + bs2[c+7]);
        *(short8v*)&xn[r * 512 + ((lane ^ (r & 7)) * 8)] = o8;
    }

    // stage B tile for ks=0 into buf 0
    {
        const short* src = wfrag + ((size_t)0 * 1536 + w * 384 + lane) * 8;
        short* dst = &bsh[0 * 12288 + (w * 384) * 8];
        #pragma unroll
        for (int uu = 0; uu < 6; ++uu)
            gload_lds16(src + uu * 512, dst + uu * 512);
    }

    f32x4 acc[24];
    #pragma unroll
    for (int ct = 0; ct < 24; ++ct) acc[ct] = (f32x4){0.f,0.f,0.f,0.f};

    const int lr = lane & 15;
    const int lg = lane >> 4;
    const int arow = w * 16 + lr;

    #pragma unroll 1
    for (int ks = 0; ks < 16; ++ks) {
        __syncthreads();   // drains staging of buf[ks&1] (waitcnt before barrier)
        if (ks < 15) {
            const int ksn = ks + 1;
            const short* src = wfrag + ((size_t)ksn * 1536 + w * 384 + lane) * 8;
            short* dst = &bsh[(ksn & 1) * 12288 + (w * 384) * 8];
            #pragma unroll
            for (int uu = 0; uu < 6; ++uu)
                gload_lds16(src + uu * 512, dst + uu * 512);
        }
        const short8v af = *(const short8v*)&xn[arow * 512 + (((ks*4 + lg) ^ (arow & 7)) * 8)];
        const short* bb = &bsh[(ks & 1) * 12288];
        #pragma unroll
        for (int ct = 0; ct < 24; ++ct) {
            const short8v bf = *(const short8v*)&bb[(ct * 64 + lane) * 8];
            acc[ct] = __builtin_amdgcn_mfma_f32_16x16x32_bf16(af, bf, acc[ct], 0, 0, 0);
        }
    }

    // epilogue: D col = ct*16+lr, rows = w*16 + lg*4 + j
    #pragma unroll
    for (int ct = 0; ct < 24; ++ct) {
        const int c = ct * 16 + lr;
        const int sel = c >> 7;
        const int h = (c >> 6) & 1;
        const int d = c & 63;
        float* dst = (sel == 0) ? q : (sel == 1) ? k : v;
        const float sc = (sel == 0) ? 0.125f : 1.0f;
        #pragma unroll
        for (int j = 0; j < 4; ++j) {
            const int grow = row0 + w * 16 + lg * 4 + j;
            const int b = grow >> 13;
            const int n = grow & (NSEQ - 1);
            dst[(((size_t)b * HH + h) * NSEQ + n) * DH + d] = acc[ct][j] * sc;
        }
    }
}

// ---------------------------------------------------------------------------
// K2: landmark means over chunks of 32 rows.
// ---------------------------------------------------------------------------
__global__ __launch_bounds__(256) void landmark_kernel(
    const float* __restrict__ q, const float* __restrict__ k,
    float* __restrict__ ql, float* __restrict__ kl)
{
    const int t = threadIdx.x;
    const int g = blockIdx.x * 4 + (t >> 6);
    const int d = t & 63;
    const int bh = g >> 8;
    const int m  = g & 255;
    const float* qb = q + ((size_t)bh * NSEQ + (size_t)m * LCH) * DH + d;
    const float* kb = k + ((size_t)bh * NSEQ + (size_t)m * LCH) * DH + d;
    float sq = 0.0f, sk = 0.0f;
    #pragma unroll
    for (int i = 0; i < LCH; ++i) { sq += qb[i*DH]; sk += kb[i*DH]; }
    ql[((size_t)bh * MLAND + m) * DH + d] = sq * (1.0f/LCH);
    kl[((size_t)bh * MLAND + m) * DH + d] = sk * (1.0f/LCH);
}

// ---------------------------------------------------------------------------
// K3: a2 = softmax(q_l @ k_l^T).
// ---------------------------------------------------------------------------
__global__ __launch_bounds__(256) void sim2_kernel(
    const float* __restrict__ ql, const float* __restrict__ kl,
    float* __restrict__ a2)
{
    const int bh = blockIdx.x >> 8;
    const int i  = blockIdx.x & 255;
    const int j  = threadIdx.x;
    __shared__ float qrow[64];
    __shared__ float red[8];
    if (j < 64) qrow[j] = ql[((size_t)bh*MLAND + i)*DH + j];
    __syncthreads();
    const float4* k4 = (const float4*)(kl + ((size_t)bh*MLAND + j)*DH);
    float s = 0.0f;
    #pragma unroll
    for (int u = 0; u < 16; ++u) {
        const float4 kv = k4[u];
        s = fmaf(qrow[u*4+0], kv.x, s);
        s = fmaf(qrow[u*4+1], kv.y, s);
        s = fmaf(qrow[u*4+2], kv.z, s);
        s = fmaf(qrow[u*4+3], kv.w, s);
    }
    float m = s;
    #pragma unroll
    for (int o = 32; o > 0; o >>= 1) m = fmaxf(m, __shfl_xor(m, o, 64));
    if ((j & 63) == 0) red[j >> 6] = m;
    __syncthreads();
    m = fmaxf(fmaxf(red[0], red[1]), fmaxf(red[2], red[3]));
    const float e = __expf(s - m);
    float l = e;
    #pragma unroll
    for (int o = 32; o > 0; o >>= 1) l += __shfl_xor(l, o, 64);
    if ((j & 63) == 0) red[4 + (j >> 6)] = l;
    __syncthreads();
    l = red[4] + red[5] + red[6] + red[7];
    a2[((size_t)bh*MLAND + i)*MLAND + j] = e / l;
}

// ---------------------------------------------------------------------------
// K4: pinv init (max of row/col abs sums, global over bh), z0 = a2^T*scale.
// ---------------------------------------------------------------------------
__global__ void initmax_kernel(unsigned int* mx) {
    if (threadIdx.x < 2) mx[threadIdx.x] = 0u;
}

__global__ __launch_bounds__(256) void pinv_sums_kernel(
    const float* __restrict__ a2, unsigned int* __restrict__ mx)
{
    const int bh = blockIdx.x;
    const int t = threadIdx.x;
    const float* A = a2 + (size_t)bh * MLAND * MLAND;
    float rs = 0.0f, cs = 0.0f;
    const float4* row4 = (const float4*)(A + (size_t)t * MLAND);
    #pragma unroll 8
    for (int u = 0; u < 64; ++u) {
        const float4 val = row4[u];
        rs += fabsf(val.x) + fabsf(val.y) + fabsf(val.z) + fabsf(val.w);
    }
    #pragma unroll 8
    for (int i = 0; i < MLAND; ++i) cs += fabsf(A[(size_t)i*MLAND + t]);
    __shared__ float red[8];
    float mrs = rs, mcs = cs;
    #pragma unroll
    for (int o = 32; o > 0; o >>= 1) {
        mrs = fmaxf(mrs, __shfl_xor(mrs, o, 64));
        mcs = fmaxf(mcs, __shfl_xor(mcs, o, 64));
    }
    if ((t & 63) == 0) { red[t>>6] = mrs; red[4+(t>>6)] = mcs; }
    __syncthreads();
    if (t == 0) {
        const float a = fmaxf(fmaxf(red[0],red[1]), fmaxf(red[2],red[3]));
        const float b = fmaxf(fmaxf(red[4],red[5]), fmaxf(red[6],red[7]));
        atomicMax(&mx[0], __float_as_uint(a));
        atomicMax(&mx[1], __float_as_uint(b));
    }
}

__global__ __launch_bounds__(256) void z0_kernel(
    const float* __restrict__ a2, const unsigned int* __restrict__ mx,
    float* __restrict__ z)
{
    const float scale = 1.0f / (__uint_as_float(mx[0]) * __uint_as_float(mx[1]));
    const size_t idx = (size_t)blockIdx.x * 256 + threadIdx.x;
    const size_t bh = idx >> 16;
    const size_t i = (idx >> 8) & 255;
    const size_t j = idx & 255;
    z[idx] = a2[(bh << 16) | (j << 8) | i] * scale;
}

// ---------------------------------------------------------------------------
// K5: batched (8x) 256x256 @ 256xNC:  C = c1*A + c2*(A@B).  (proven r1/r2)
// ---------------------------------------------------------------------------
__global__ __launch_bounds__(256) void mm256_kernel(
    float* __restrict__ C, const float* __restrict__ A,
    const float* __restrict__ Bm, float c1, float c2, int NC)
{
    __shared__ float As[32][65];
    __shared__ float Bs[64][68];
    const int bh = blockIdx.z;
    const int row0 = blockIdx.y * 32;
    const int col0 = blockIdx.x * 64;
    const float* Ab = A + (size_t)bh * MLAND * MLAND;
    const float* Bb = Bm + (size_t)bh * MLAND * NC;
    const int t = threadIdx.x;
    const int tc = (t & 15) * 4;
    const int tr = (t >> 4) * 2;
    float acc[2][4] = {{0,0,0,0},{0,0,0,0}};
    for (int k0 = 0; k0 < 256; k0 += 64) {
        #pragma unroll
        for (int u = 0; u < 2; ++u) {
            const int idx = t + u*256;
            const int r = idx >> 4, c4 = (idx & 15) * 4;
            const float4 val = *(const float4*)(Ab + (size_t)(row0 + r) * MLAND + k0 + c4);
            As[r][c4+0] = val.x; As[r][c4+1] = val.y;
            As[r][c4+2] = val.z; As[r][c4+3] = val.w;
        }
        #pragma unroll
        for (int u = 0; u < 4; ++u) {
            const int idx = t + u*256;
            const int r = idx >> 4, c4 = (idx & 15) * 4;
            *(float4*)&Bs[r][c4] = *(const float4*)(Bb + (size_t)(k0 + r) * NC + col0 + c4);
        }
        __syncthreads();
        #pragma unroll 8
        for (int kk = 0; kk < 64; ++kk) {
            const float a0 = As[tr][kk];
            const float a1 = As[tr+1][kk];
            const float4 b4 = *(const float4*)&Bs[kk][tc];
            acc[0][0] = fmaf(a0, b4.x, acc[0][0]);
            acc[0][1] = fmaf(a0, b4.y, acc[0][1]);
            acc[0][2] = fmaf(a0, b4.z, acc[0][2]);
            acc[0][3] = fmaf(a0, b4.w, acc[0][3]);
            acc[1][0] = fmaf(a1, b4.x, acc[1][0]);
            acc[1][1] = fmaf(a1, b4.y, acc[1][1]);
            acc[1][2] = fmaf(a1, b4.z, acc[1][2]);
            acc[1][3] = fmaf(a1, b4.w, acc[1][3]);
        }
        __syncthreads();
    }
    #pragma unroll
    for (int i = 0; i < 2; ++i) {
        const int r = row0 + tr + i;
        #pragma unroll
        for (int j = 0; j < 4; ++j) {
            const int c = col0 + tc + j;
            float val = c2 * acc[i][j];
            if (c1 != 0.0f) val = fmaf(c1, Ab[(size_t)r * MLAND + c], val);
            C[((size_t)bh * MLAND + r) * NC + c] = val;
        }
    }
}

// ---------------------------------------------------------------------------
// K6: flash-style a3v partials (fp32).
// ---------------------------------------------------------------------------
__global__ __launch_bounds__(256, 1) void sim3_kernel(
    const float* __restrict__ ql, const float* __restrict__ kg,
    const float* __restrict__ vg, float* __restrict__ po,
    float* __restrict__ pm, float* __restrict__ pl)
{
    __shared__ float ks[64][68];
    __shared__ float vs[64][68];
    const int ch = blockIdx.x;
    const int bh = blockIdx.y;
    const int t = threadIdx.x;
    float4 q4[16];
    {
        const float* qr = ql + ((size_t)bh * MLAND + t) * DH;
        #pragma unroll
        for (int u = 0; u < 16; ++u) q4[u] = *(const float4*)(qr + u*4);
    }
    float4 o4[16];
    #pragma unroll
    for (int u = 0; u < 16; ++u) o4[u] = make_float4(0.f,0.f,0.f,0.f);
    float m = -1e30f, l = 0.0f;

    #pragma unroll 1
    for (int sc = 0; sc < 4; ++sc) {
        const int j0 = ch * 256 + sc * 64;
        #pragma unroll
        for (int u = 0; u < 4; ++u) {
            const int idx = t + u*256;
            const int r = idx >> 4, c4 = (idx & 15) * 4;
            *(float4*)&ks[r][c4] = *(const float4*)(kg + ((size_t)bh*NSEQ + j0 + r)*DH + c4);
            *(float4*)&vs[r][c4] = *(const float4*)(vg + ((size_t)bh*NSEQ + j0 + r)*DH + c4);
        }
        __syncthreads();
        #pragma unroll 1
        for (int b16 = 0; b16 < 4; ++b16) {
            float s[16];
            #pragma unroll
            for (int c = 0; c < 16; ++c) {
                const int cc = b16*16 + c;
                float a = 0.0f;
                #pragma unroll
                for (int u = 0; u < 16; ++u) {
                    const float4 kv = *(const float4*)&ks[cc][u*4];
                    a = fmaf(q4[u].x, kv.x, a);
                    a = fmaf(q4[u].y, kv.y, a);
                    a = fmaf(q4[u].z, kv.z, a);
                    a = fmaf(q4[u].w, kv.w, a);
                }
                s[c] = a;
            }
            float bm = s[0];
            #pragma unroll
            for (int c = 1; c < 16; ++c) bm = fmaxf(bm, s[c]);
            const float mn = fmaxf(m, bm);
            const float scale = __expf(m - mn);
            l *= scale;
            #pragma unroll
            for (int u = 0; u < 16; ++u) {
                o4[u].x *= scale; o4[u].y *= scale;
                o4[u].z *= scale; o4[u].w *= scale;
            }
            #pragma unroll
            for (int c = 0; c < 16; ++c) {
                const int cc = b16*16 + c;
                const float p = __expf(s[c] - mn);
                l += p;
                #pragma unroll
                for (int u = 0; u < 16; ++u) {
                    const float4 vv = *(const float4*)&vs[cc][u*4];
                    o4[u].x = fmaf(p, vv.x, o4[u].x);
                    o4[u].y = fmaf(p, vv.y, o4[u].y);
                    o4[u].z = fmaf(p, vv.z, o4[u].z);
                    o4[u].w = fmaf(p, vv.w, o4[u].w);
                }
            }
            m = mn;
        }
        __syncthreads();
    }
    float* od = po + (((size_t)bh*32 + ch) * MLAND + t) * DH;
    #pragma unroll
    for (int u = 0; u < 16; ++u) *(float4*)(od + u*4) = o4[u];
    pm[((size_t)bh*32 + ch) * MLAND + t] = m;
    pl[((size_t)bh*32 + ch) * MLAND + t] = l;
}

// K7: merge 32 chunk partials -> a3v
__global__ __launch_bounds__(256) void sim3red_kernel(
    const float* __restrict__ po, const float* __restrict__ pm,
    const float* __restrict__ pl, float* __restrict__ a3v)
{
    const int g = blockIdx.x * 4 + (threadIdx.x >> 6);
    const int d = threadIdx.x & 63;
    const int bh = g >> 8;
    const int r = g & 255;
    float M = -1e30f;
    #pragma unroll
    for (int c = 0; c < 32; ++c)
        M = fmaxf(M, pm[((size_t)bh*32 + c)*MLAND + r]);
    float L = 0.0f, o = 0.0f;
    #pragma unroll 1
    for (int c = 0; c < 32; ++c) {
        const float w = __expf(pm[((size_t)bh*32 + c)*MLAND + r] - M);
        L = fmaf(pl[((size_t)bh*32 + c)*MLAND + r], w, L);
        o = fmaf(po[(((size_t)bh*32 + c)*MLAND + r)*DH + d], w, o);
    }
    a3v[((size_t)bh*MLAND + r)*DH + d] = o / L;
}

// ---------------------------------------------------------------------------
// K8a/b: kl -> bf16; W -> bf16 transposed.
// ---------------------------------------------------------------------------
__global__ __launch_bounds__(256) void packkl_kernel(
    const float* __restrict__ klm, short* __restrict__ klb)
{
    const int idx = blockIdx.x * 256 + threadIdx.x;
    klb[idx] = f2bf(klm[idx]);
}

__global__ __launch_bounds__(256) void packwt_kernel(
    const float* __restrict__ Wm, short* __restrict__ wtb)
{
    const int idx = blockIdx.x * 256 + threadIdx.x;
    const int bh = idx >> 14;
    const int rem = idx & 16383;
    const int d = rem >> 8;
    const int m = rem & 255;
    wtb[idx] = f2bf(Wm[((size_t)bh * MLAND + m) * DH + d]);
}

// ---------------------------------------------------------------------------
// K8: MFMA flash attention vs 256 landmarks (proven round 2).
// ---------------------------------------------------------------------------
__global__ __launch_bounds__(256, 2) void final1_mfma_kernel(
    const float* __restrict__ q, const short* __restrict__ klb,
    const short* __restrict__ wtb, float* __restrict__ inner)
{
    __shared__ short ldsA[16384];
    __shared__ short ldsW[16384];
    const int bh = blockIdx.y;
    const int b = bh >> 1;
    const int h = bh & 1;
    const int t = threadIdx.x;
    const int w = t >> 6;
    const int l = t & 63;
    const int lr = l & 15;
    const int lg = l >> 4;

    {
        const short* klsrc = klb + (size_t)bh * 16384;
        const short* wtsrc = wtb + (size_t)bh * 16384;
        #pragma unroll
        for (int u = 0; u < 8; ++u) {
            const int gi = t + u * 256;
            const int m  = gi >> 3, sl = gi & 7;
            *(short8v*)&ldsA[m*64 + (sl ^ (m & 7))*8] =
                *(const short8v*)(klsrc + gi*8);
            const int dd = gi >> 5, sw = gi & 31;
            *(short8v*)&ldsW[dd*256 + (sw ^ (dd & 7))*8] =
                *(const short8v*)(wtsrc + gi*8);
        }
    }
    __syncthreads();

    const int n = blockIdx.x * 64 + w * 16 + lr;
    short8v qb0, qb1;
    {
        const float* qr = q + ((size_t)bh * NSEQ + n) * DH + lg * 8;
        const float4 f0 = *(const float4*)qr;
        const float4 f1 = *(const float4*)(qr + 4);
        const float4 f2 = *(const float4*)(qr + 32);
        const float4 f3 = *(const float4*)(qr + 36);
        qb0[0]=f2bf(f0.x); qb0[1]=f2bf(f0.y); qb0[2]=f2bf(f0.z); qb0[3]=f2bf(f0.w);
        qb0[4]=f2bf(f1.x); qb0[5]=f2bf(f1.y); qb0[6]=f2bf(f1.z); qb0[7]=f2bf(f1.w);
        qb1[0]=f2bf(f2.x); qb1[1]=f2bf(f2.y); qb1[2]=f2bf(f2.z); qb1[3]=f2bf(f2.w);
        qb1[4]=f2bf(f3.x); qb1[5]=f2bf(f3.y); qb1[6]=f2bf(f3.z); qb1[7]=f2bf(f3.w);
    }

    f32x4 accS[16];
    #pragma unroll
    for (int mt = 0; mt < 16; ++mt) accS[mt] = (f32x4){0.f,0.f,0.f,0.f};
    const int s8 = lr & 7;
    #pragma unroll
    for (int mt = 0; mt < 16; ++mt) {
        const int m = mt * 16 + lr;
        const short8v a0 = *(const short8v*)&ldsA[m*64 + ((0*4 + lg) ^ s8)*8];
        const short8v a1 = *(const short8v*)&ldsA[m*64 + ((1*4 + lg) ^ s8)*8];
        accS[mt] = __builtin_amdgcn_mfma_f32_16x16x32_bf16(a0, qb0, accS[mt], 0, 0, 0);
        accS[mt] = __builtin_amdgcn_mfma_f32_16x16x32_bf16(a1, qb1, accS[mt], 0, 0, 0);
    }

    float mloc = -1e30f;
    #pragma unroll
    for (int mt = 0; mt < 16; ++mt)
        #pragma unroll
        for (int j = 0; j < 4; ++j) mloc = fmaxf(mloc, accS[mt][j]);
    mloc = fmaxf(mloc, __shfl_xor(mloc, 16, 64));
    mloc = fmaxf(mloc, __shfl_xor(mloc, 32, 64));
    float lsum = 0.0f;
    #pragma unroll
    for (int mt = 0; mt < 16; ++mt)
        #pragma unroll
        for (int j = 0; j < 4; ++j) {
            const float p = __expf(accS[mt][j] - mloc);
            accS[mt][j] = p;
            lsum += p;
        }
    lsum += __shfl_xor(lsum, 16, 64);
    lsum += __shfl_xor(lsum, 32, 64);

    __syncthreads();

    {
        short* pw = ldsA + w * 4096;
        #pragma unroll
        for (int mt = 0; mt < 16; ++mt) {
            short4v pk;
            pk[0] = f2bf(accS[mt][0]); pk[1] = f2bf(accS[mt][1]);
            pk[2] = f2bf(accS[mt][2]); pk[3] = f2bf(accS[mt][3]);
            const int byteoff = (mt*32 + lg*8) ^ (s8 << 4);
            *(short4v*)&pw[lr*256 + (byteoff >> 1)] = pk;
        }
    }
    __syncthreads();

    short8v pb[8];
    {
        const short* pw = ldsA + w * 4096;
        #pragma unroll
        for (int kc = 0; kc < 8; ++kc) {
            const int byteoff = (kc*64 + lg*16) ^ (s8 << 4);
            pb[kc] = *(const short8v*)&pw[lr*256 + (byteoff >> 1)];
        }
    }
    f32x4 accO[4];
    #pragma unroll
    for (int dt = 0; dt < 4; ++dt) accO[dt] = (f32x4){0.f,0.f,0.f,0.f};
    #pragma unroll
    for (int dt = 0; dt < 4; ++dt) {
        const int d = dt * 16 + lr;
        #pragma unroll
        for (int kc = 0; kc < 8; ++kc) {
            const short8v wa = *(const short8v*)&ldsW[d*256 + (((kc*64 + lg*16) ^ (s8 << 4)) >> 1)];
            accO[dt] = __builtin_amdgcn_mfma_f32_16x16x32_bf16(wa, pb[kc], accO[dt], 0, 0, 0);
        }
    }

    const float rl = 1.0f / lsum;
    float* ob = inner + ((size_t)b * NSEQ + n) * INNER + h * DH + lg * 4;
    #pragma unroll
    for (int dt = 0; dt < 4; ++dt) {
        float4 o;
        o.x = accO[dt][0] * rl; o.y = accO[dt][1] * rl;
        o.z = accO[dt][2] * rl; o.w = accO[dt][3] * rl;
        *(float4*)(ob + dt * 16) = o;
    }
}

// ---------------------------------------------------------------------------
// K9: depthwise conv-33 residual add.
// ---------------------------------------------------------------------------
__global__ __launch_bounds__(256) void conv_add_kernel(
    const float* __restrict__ vg, const float* __restrict__ wres,
    float* __restrict__ inner)
{
    __shared__ float wr[KER];
    const int bh = blockIdx.y;
    const int b = bh >> 1;
    const int h = bh & 1;
    const int t = threadIdx.x;
    if (t < KER) wr[t] = wres[h*KER + t];
    __syncthreads();
    const int d = t & 63;
    const int g = t >> 6;
    const int n0 = blockIdx.x * 128;
    #pragma unroll 1
    for (int i = 0; i < 32; ++i) {
        const int n = n0 + g + i*4;
        float acc = 0.0f;
        #pragma unroll
        for (int tt = 0; tt < KER; ++tt) {
            const int nn = n - 16 + tt;
            if (nn >= 0 && nn < NSEQ)
                acc = fmaf(vg[((size_t)bh*NSEQ + nn)*DH + d], wr[tt], acc);
        }
        const size_t idx = ((size_t)b*NSEQ + n)*INNER + h*DH + d;
        inner[idx] += acc;
    }
}

// ---------------------------------------------------------------------------
// K10: final2 bf16 MFMA: out = innerb @ wout + bout + x.
// ---------------------------------------------------------------------------
__global__ __launch_bounds__(256) void final2_mfma_kernel(
    const short* __restrict__ innerb, const short* __restrict__ wfrag2,
    const float* __restrict__ bout, const float* __restrict__ x,
    float* __restrict__ out)
{
    __shared__ short ia[64 * 128];   // 16KB, swizzled
    const int t = threadIdx.x;
    const int w = t >> 6;
    const int lane = t & 63;
    const size_t row0 = (size_t)blockIdx.x * 64;

    #pragma unroll
    for (int u = 0; u < 4; ++u) {
        const int idx = u * 256 + t;
        const int r = idx >> 4, sl = idx & 15;
        *(short8v*)&ia[r * 128 + ((sl ^ (r & 7)) * 8)] =
            *(const short8v*)&innerb[(row0 + r) * 128 + sl * 8];
    }
    __syncthreads();

    const int lr = lane & 15;
    const int lg = lane >> 4;
    const int arow = w * 16 + lr;
    f32x4 acc[32];
    #pragma unroll
    for (int ct = 0; ct < 32; ++ct) acc[ct] = (f32x4){0.f,0.f,0.f,0.f};

    #pragma unroll
    for (int ks = 0; ks < 4; ++ks) {
        const short8v af = *(const short8v*)&ia[arow * 128 + (((ks*4 + lg) ^ (arow & 7)) * 8)];
        #pragma unroll
        for (int ct = 0; ct < 32; ++ct) {
            const short8v bf = *(const short8v*)&wfrag2[((size_t)(ks*32 + ct)*64 + lane) * 8];
            acc[ct] = __builtin_amdgcn_mfma_f32_16x16x32_bf16(af, bf, acc[ct], 0, 0, 0);
        }
    }

    #pragma unroll
    for (int ct = 0; ct < 32; ++ct) {
        const int c = ct * 16 + lr;
        const float bo = bout[c];
        #pragma unroll
        for (int j = 0; j < 4; ++j) {
            const size_t row = row0 + w * 16 + lg * 4 + j;
            out[row * DMODEL + c] = acc[ct][j] + bo + x[row * DMODEL + c];
        }
    }
}

// ---------------------------------------------------------------------------
extern "C" void kernel_launch(void* const* d_in, const int* in_sizes, int n_in,
                              void* d_out, int out_size, void* d_ws, size_t ws_size,
                              hipStream_t stream)
{
    const float* x     = (const float*)d_in[0];
    const float* gamma = (const float*)d_in[1];
    const float* beta  = (const float*)d_in[2];
    const float* wqkv  = (const float*)d_in[3];
    const float* wout  = (const float*)d_in[4];
    const float* bout  = (const float*)d_in[5];
    const float* wres  = (const float*)d_in[6];
    float* out = (float*)d_out;

    float* ws = (float*)d_ws;
    const size_t QS = (size_t)BH * NSEQ * DH;       // 4194304
    const size_t LS = (size_t)BH * MLAND * DH;      // 131072
    const size_t MS = (size_t)BH * MLAND * MLAND;   // 524288
    float* q    = ws;
    float* kbuf = q + QS;
    float* vbuf = kbuf + QS;
    float* ql   = vbuf + QS;
    float* klm  = ql + LS;
    float* a2   = klm + LS;
    float* zA   = a2 + MS;
    float* zB   = zA + MS;
    float* xz   = zB + MS;
    float* t1   = xz + MS;
    float* t2   = t1 + MS;
    float* a3v  = t2 + MS;
    float* Wm   = a3v + LS;
    float* po   = Wm + LS;
    float* pm   = po + QS;
    float* pl   = pm + (size_t)BH * 32 * MLAND;
    unsigned int* mx = (unsigned int*)(pl + (size_t)BH * 32 * MLAND);
    float* inner = po;                     // po dead after sim3red
    short* klb = (short*)kbuf;             // kbuf dead after sim3
    short* wtb = (short*)kbuf + LS;
    short* wfrag  = (short*)pm;            // pm/pl live only sim3..sim3red
    short* wfrag2 = (short*)a3v;           // a3v dead after last mm256 (Wm)
    short* innerb = (short*)q;             // q dead after final1

    // wqkv pack (into pm region; consumed by ln_qkv before sim3 writes pm)
    pack_wqkv_kernel<<<96, 256, 0, stream>>>(wqkv, wfrag);
    ln_qkv_mfma_kernel<<<512, 256, 0, stream>>>(x, gamma, beta, wfrag, q, kbuf, vbuf);
    landmark_kernel<<<(BH*MLAND)/4, 256, 0, stream>>>(q, kbuf, ql, klm);
    sim2_kernel<<<BH*MLAND, 256, 0, stream>>>(ql, klm, a2);

    // a3v (uses kbuf/vbuf; kbuf dead afterwards)
    sim3_kernel<<<dim3(32, BH), 256, 0, stream>>>(ql, kbuf, vbuf, po, pm, pl);
    sim3red_kernel<<<(BH*MLAND)/4, 256, 0, stream>>>(po, pm, pl, a3v);

    // pinv of a2 (6 Newton iterations, fp32, proven 25-launch chain)
    initmax_kernel<<<1, 64, 0, stream>>>(mx);
    pinv_sums_kernel<<<BH, 256, 0, stream>>>(a2, mx);
    z0_kernel<<<(unsigned)(MS/256), 256, 0, stream>>>(a2, mx, zA);
    float* za = zA;
    float* zb = zB;
    for (int it = 0; it < 6; ++it) {
        mm256_kernel<<<dim3(4,8,BH), 256, 0, stream>>>(xz, a2, za, 0.0f, 1.0f, 256);
        mm256_kernel<<<dim3(4,8,BH), 256, 0, stream>>>(t1, xz, xz, 7.0f, -1.0f, 256);
        mm256_kernel<<<dim3(4,8,BH), 256, 0, stream>>>(t2, xz, t1, 15.0f, -1.0f, 256);
        mm256_kernel<<<dim3(4,8,BH), 256, 0, stream>>>(zb, za, t2, 3.25f, -0.25f, 256);
        float* tmp = za; za = zb; zb = tmp;
    }
    // W = a2_inv @ a3v
    mm256_kernel<<<dim3(1,8,BH), 256, 0, stream>>>(Wm, za, a3v, 0.0f, 1.0f, 64);

    // packs (wfrag2 aliases a3v -> only after the Wm stage consumed a3v)
    pack_wout_kernel<<<32, 256, 0, stream>>>(wout, wfrag2);
    packkl_kernel<<<(unsigned)(LS/256), 256, 0, stream>>>(klm, klb);
    packwt_kernel<<<(unsigned)(LS/256), 256, 0, stream>>>(Wm, wtb);

    final1_mfma_kernel<<<dim3(NSEQ/64, BH), 256, 0, stream>>>(q, klb, wtb, inner);
    conv_add_kernel<<<dim3(NSEQ/128, BH), 256, 0, stream>>>(vbuf, wres, inner);
    pack_inner_kernel<<<2048, 256, 0, stream>>>(inner, innerb);
    final2_mfma_kernel<<<512, 256, 0, stream>>>(innerb, wfrag2, bout, x, out);
}